// Round 1
// baseline (6728.457 us; speedup 1.0000x reference)
//
#include <hip/hip_runtime.h>
#include <cstdio>
#include <cmath>

// ---------------- problem constants ----------------
constexpr int HH = 512;      // hidden
constexpr int MM_T = 104;    // timesteps
constexpr int BB = 512;      // batch
constexpr int BM = BB * MM_T;       // 53248 rows
constexpr int DEPTH = 5;
constexpr float BN_EPS = 1e-5f;

// ---------------- workspace layout (bytes) ----------------
constexpr size_t SZ_ACT  = (size_t)BM * HH * 4;            // 109,051,904
constexpr size_t SZ_MAT5 = (size_t)5 * 512 * 512 * 4;      // 5,242,880
constexpr size_t OFF_ACT0 = 0;
constexpr size_t OFF_ACT1 = OFF_ACT0 + SZ_ACT;
constexpr size_t OFF_X    = OFF_ACT1 + SZ_ACT;             // X = 0.1*A  -> later A2
constexpr size_t OFF_T1   = OFF_X   + SZ_MAT5;             // temp -> later A4
constexpr size_t OFF_T2   = OFF_T1  + SZ_MAT5;             // temp -> later A8
constexpr size_t OFF_E    = OFF_T2  + SZ_MAT5;             // E = expm(0.1A) - I
constexpr size_t OFF_MW   = OFF_E   + SZ_MAT5;             // S -> becomes inv(S)
constexpr size_t OFF_ROWT = OFF_MW  + SZ_MAT5;             // [5][64][512]
constexpr size_t OFF_COLS = OFF_ROWT + 655360;             // [5][512][64]
constexpr size_t OFF_PIVI = OFF_COLS + 655360;             // [5][64][64]
constexpr size_t OFF_WT   = OFF_PIVI + 81920;              // conv wt transposed [1536][512]
constexpr size_t OFF_PJT  = OFF_WT  + 3145728;             // proj_w^T
constexpr size_t OFF_F1T  = OFF_PJT + 1048576;             // fc1_w^T
constexpr size_t OFF_G    = OFF_F1T + 1048576;             // g[b][h]
constexpr size_t OFF_POOL = OFF_G   + 1048576;             // pooled[b][o]
constexpr size_t OFF_Z    = OFF_POOL + 1048576;            // fc1 out
constexpr size_t OFF_ST   = OFF_Z   + 1048576;             // fp64 stats [6][2][512]
constexpr size_t OFF_SC   = OFF_ST  + 49152;               // scale/shift [5][2][512] f32
constexpr size_t OFF_U    = OFF_SC  + 20480;               // u[5][512]
constexpr size_t OFF_SV   = OFF_U   + 10240;               // residual r[5][512]
constexpr size_t OFF_V    = OFF_SV  + 10240;               // V[5][8][512]
constexpr size_t OFF_WV   = OFF_V   + 81920;               // W[5][13][512]
constexpr size_t OFF_TRM  = OFF_WV  + 133120;              // terms[5][104]
constexpr size_t OFF_S    = OFF_TRM + 2304;                // s[104] + sbar
constexpr size_t WS_NEED  = OFF_S + 512;

// ================= ZOH: build X = 0.1*A, S = A + 0.001 I =================
__global__ void k_build(const float* __restrict__ Aall, float* __restrict__ X, float* __restrict__ MW)
{
    long i = (long)blockIdx.x * 256 + threadIdx.x;     // 5*262144 total
    float a = Aall[i];
    X[i] = 0.1f * a;
    int rc = (int)(i & 262143);
    int r = rc >> 9, c = rc & 511;
    MW[i] = a + ((r == c) ? 0.001f : 0.0f);
}

// ================= generic batched 64x64-tile fp32 matmul =================
// C[M,N] = A[M,K] * B[K,N] with epilogue modes.
// mode 0: C = alpha*acc
// mode 1: C = acc + 2*aux + I            (A2 = E*E + 2E + I; aux ld = 512)
// mode 2: C = alpha*acc + beta*aux       (expm Horner; aux ld = 512)
// mode 3: GJ row-scale: C = acc, but cols [pc,pc+64) = aux[row][col-pc] (aux=PivInv, ld 64)
// mode 4: GJ elim: C = (col in pcols ? 0 : C_old) - acc ; rows [pr,pr+64) skipped
// mode 5: C = acc + aux[col]*aux2[0]
// mode 6: C = acc + aux[col]
__global__ __launch_bounds__(256) void k_mm(
    const float* __restrict__ A, long sA, int lda,
    const float* __restrict__ Bm, long sB, int ldb,
    float* __restrict__ C, long sC, int ldc,
    int K, int mode, float alpha, float beta,
    const float* __restrict__ aux, long sAux,
    const float* __restrict__ aux2, int pc, int pr)
{
    __shared__ float sm[2 * 32 * 68];
    float* As = sm;
    float* Bs = sm + 32 * 68;
    int z = blockIdx.z;
    A  += (long)z * sA;
    Bm += (long)z * sB;
    C  += (long)z * sC;
    if (aux) aux += (long)z * sAux;
    int m0 = blockIdx.x * 64, n0 = blockIdx.y * 64;
    if (mode == 4 && m0 == pr) return;
    int tid = threadIdx.x;
    int tx = tid & 15, ty = tid >> 4;
    float acc[4][4] = {};
    for (int k0 = 0; k0 < K; k0 += 32) {
        __syncthreads();
#pragma unroll
        for (int it = 0; it < 2; ++it) {
            int s = it * 256 + tid;
            int mm = s >> 3, k4 = (s & 7) * 4;
            float4 v = *(const float4*)&A[(long)(m0 + mm) * lda + k0 + k4];
            As[(k4 + 0) * 68 + mm] = v.x;
            As[(k4 + 1) * 68 + mm] = v.y;
            As[(k4 + 2) * 68 + mm] = v.z;
            As[(k4 + 3) * 68 + mm] = v.w;
        }
#pragma unroll
        for (int it = 0; it < 2; ++it) {
            int s = it * 256 + tid;
            int kk = s >> 4, n4 = (s & 15) * 4;
            *(float4*)&Bs[kk * 68 + n4] = *(const float4*)&Bm[(long)(k0 + kk) * ldb + n0 + n4];
        }
        __syncthreads();
#pragma unroll 8
        for (int kk = 0; kk < 32; ++kk) {
            float4 a = *(const float4*)&As[kk * 68 + ty * 4];
            float4 b = *(const float4*)&Bs[kk * 68 + tx * 4];
            float av[4] = {a.x, a.y, a.z, a.w};
            float bv[4] = {b.x, b.y, b.z, b.w};
#pragma unroll
            for (int i = 0; i < 4; ++i)
#pragma unroll
                for (int j = 0; j < 4; ++j)
                    acc[i][j] = fmaf(av[i], bv[j], acc[i][j]);
        }
    }
    float sc2 = (mode == 5) ? aux2[0] : 0.0f;
#pragma unroll
    for (int i = 0; i < 4; ++i) {
        int row = m0 + ty * 4 + i;
        int col0 = n0 + tx * 4;
        long base = (long)row * ldc + col0;
        float v[4];
#pragma unroll
        for (int j = 0; j < 4; ++j) v[j] = acc[i][j];
        if (mode == 0) {
            for (int j = 0; j < 4; ++j) v[j] *= alpha;
        } else if (mode == 1) {
            for (int j = 0; j < 4; ++j) {
                int col = col0 + j;
                v[j] = v[j] + 2.0f * aux[(long)row * 512 + col] + ((row == col) ? 1.0f : 0.0f);
            }
        } else if (mode == 2) {
            for (int j = 0; j < 4; ++j)
                v[j] = alpha * v[j] + beta * aux[(long)row * 512 + col0 + j];
        } else if (mode == 3) {
            bool inP = (col0 >= pc && col0 < pc + 64);
            if (inP)
                for (int j = 0; j < 4; ++j) v[j] = aux[row * 64 + (col0 + j - pc)];
        } else if (mode == 4) {
            bool inP = (col0 >= pc && col0 < pc + 64);
            float4 oldv = *(const float4*)&C[base];
            float ov[4] = {oldv.x, oldv.y, oldv.z, oldv.w};
            for (int j = 0; j < 4; ++j) v[j] = (inP ? 0.0f : ov[j]) - v[j];
        } else if (mode == 5) {
            for (int j = 0; j < 4; ++j) v[j] += aux[col0 + j] * sc2;
        } else if (mode == 6) {
            for (int j = 0; j < 4; ++j) v[j] += aux[col0 + j];
        }
        *(float4*)&C[base] = make_float4(v[0], v[1], v[2], v[3]);
    }
}

// ================= pivoted 64x64 Gauss-Jordan inverse in LDS =================
__global__ __launch_bounds__(256) void k_inv64(float* __restrict__ MW, int pblk, float* __restrict__ PIVI)
{
    __shared__ float mat[64][65];
    __shared__ int perm[64];
    __shared__ int pividx;
    int z = blockIdx.x;
    float* Mg = MW + (long)z * 262144 + (long)pblk * 64 * 512 + pblk * 64;
    int tid = threadIdx.x;
    for (int it = 0; it < 16; ++it) {
        int idx = it * 256 + tid;
        int r = idx >> 6, c = idx & 63;
        mat[r][c] = Mg[r * 512 + c];
    }
    __syncthreads();
    for (int j = 0; j < 64; ++j) {
        if (tid == 0) {
            int best = j; float bv = fabsf(mat[j][j]);
            for (int i = j + 1; i < 64; ++i) {
                float a = fabsf(mat[i][j]);
                if (a > bv) { bv = a; best = i; }
            }
            perm[j] = best; pividx = best;
        }
        __syncthreads();
        int r = pividx;
        if (r != j && tid < 64) {
            float t = mat[j][tid]; mat[j][tid] = mat[r][tid]; mat[r][tid] = t;
        }
        __syncthreads();
        float pv = mat[j][j];
        __syncthreads();
        float d = 1.0f / pv;
        if (tid < 64) mat[j][tid] = (tid == j) ? d : mat[j][tid] * d;
        __syncthreads();
        __shared__ float fv[64];
        if (tid < 64) fv[tid] = mat[tid][j];
        __syncthreads();
        {
            int i = tid & 63, cc = tid >> 6;
            if (i != j) {
                float f = fv[i];
#pragma unroll
                for (int c0 = 0; c0 < 16; ++c0) {
                    int c = cc * 16 + c0;
                    float val = mat[i][c] - f * mat[j][c];
                    if (c == j) val = -f * d;
                    mat[i][c] = val;
                }
            }
        }
        __syncthreads();
    }
    for (int j = 63; j >= 0; --j) {
        int r = perm[j];
        if (r != j && tid < 64) {
            float t = mat[tid][j]; mat[tid][j] = mat[tid][r]; mat[tid][r] = t;
        }
        __syncthreads();
    }
    float* Pg = PIVI + z * 4096;
    for (int it = 0; it < 16; ++it) {
        int idx = it * 256 + tid;
        int r = idx >> 6, c = idx & 63;
        Pg[r * 64 + c] = mat[r][c];
    }
}

__global__ void k_copycol(const float* __restrict__ MW, float* __restrict__ COLS, int pc)
{
    int idx = blockIdx.x * 256 + threadIdx.x;   // 163840
    int z = idx >> 15, rem = idx & 32767;
    int i = rem >> 6, c = rem & 63;
    COLS[idx] = MW[(long)z * 262144 + (long)i * 512 + pc + c];
}
__global__ void k_copyrow(float* __restrict__ MW, const float* __restrict__ ROWT, int pr)
{
    int idx = blockIdx.x * 256 + threadIdx.x;   // 163840
    int z = idx >> 15, rem = idx & 32767;
    int r = rem >> 9, c = rem & 511;
    MW[(long)z * 262144 + (long)(pr + r) * 512 + c] = ROWT[idx];
}
__global__ void k_copyW0(const float* __restrict__ Call, float* __restrict__ WV)
{
    int idx = blockIdx.x * 256 + threadIdx.x;   // 2560
    int z = idx >> 9, i = idx & 511;
    WV[z * 6656 + i] = Call[idx];
}

// ================= batched matvec: y = alpha*(A x) + beta*x  (variants) =================
__global__ void k_matvecA(const float* __restrict__ A, long sA,
                          const float* __restrict__ x, long sx,
                          float* __restrict__ y, long sy,
                          const float* __restrict__ sub, long ssub,
                          float alpha, float beta, int accum)
{
    int row = blockIdx.x, z = blockIdx.y, lane = threadIdx.x;
    A += (long)z * sA; x += (long)z * sx; y += (long)z * sy;
    if (sub) sub += (long)z * ssub;
    const float* ar = A + (long)row * 512;
    double acc = 0.0;
#pragma unroll
    for (int m = 0; m < 8; ++m) {
        int k = lane + m * 64;
        acc += (double)ar[k] * (double)x[k];
    }
    for (int off = 32; off; off >>= 1) acc += __shfl_down(acc, off);
    if (lane == 0) {
        float val = alpha * (float)acc + beta * x[row];
        if (sub) val = sub[row] - val;
        if (accum) y[row] += val; else y[row] = val;
    }
}

// w' = w^T * A8   (coalesced over output index)
__global__ __launch_bounds__(512) void k_matvecT(const float* __restrict__ A8, long sA,
                                                 const float* __restrict__ win, long swin,
                                                 float* __restrict__ wout, long swout)
{
    __shared__ float wl[512];
    int z = blockIdx.x, tid = threadIdx.x;
    A8 += (long)z * sA;
    wl[tid] = win[(long)z * swin + tid];
    __syncthreads();
    double acc = 0.0;
#pragma unroll 8
    for (int j = 0; j < 512; ++j)
        acc += (double)A8[(long)j * 512 + tid] * (double)wl[j];
    wout[(long)z * swout + tid] = (float)acc;
}

// terms[z][8j+i] = W[z][j] . V[z][i]
__global__ void k_terms(const float* __restrict__ WV, const float* __restrict__ V, float* __restrict__ terms)
{
    int z = blockIdx.x, tid = threadIdx.x;
    int lane = tid & 63, wv = tid >> 6;
    for (int d = wv; d < 104; d += 4) {
        int j = d >> 3, i = d & 7;
        const float* wp = WV + z * 6656 + j * 512;
        const float* vp = V + z * 4096 + i * 512;
        float acc = 0.0f;
#pragma unroll
        for (int m = 0; m < 8; ++m) {
            int k = lane + m * 64;
            acc += wp[k] * vp[k];
        }
        for (int off = 32; off; off >>= 1) acc += __shfl_down(acc, off);
        if (lane == 0) terms[z * 104 + d] = acc;
    }
}

// s[t] = prod_l flip(terms_l)[t]/(||terms_l||+1e-6);  s[104] = mean_t s[t]
__global__ __launch_bounds__(128) void k_skernel(const float* __restrict__ terms, float* __restrict__ svec)
{
    __shared__ float red[128];
    __shared__ float invn[5];
    int tid = threadIdx.x;
    for (int l = 0; l < 5; ++l) {
        float v = (tid < 104) ? terms[l * 104 + tid] : 0.0f;
        red[tid] = v * v;
        __syncthreads();
        for (int off = 64; off; off >>= 1) { if (tid < off) red[tid] += red[tid + off]; __syncthreads(); }
        if (tid == 0) invn[l] = 1.0f / (sqrtf(red[0]) + 1e-6f);
        __syncthreads();
    }
    float s = 0.0f;
    if (tid < 104) {
        s = 1.0f;
        for (int l = 0; l < 5; ++l) s *= terms[l * 104 + (103 - tid)] * invn[l];
        svec[tid] = s;
    }
    red[tid] = (tid < 104) ? s : 0.0f;
    __syncthreads();
    for (int off = 64; off; off >>= 1) { if (tid < off) red[tid] += red[tid + off]; __syncthreads(); }
    if (tid == 0) svec[104] = red[0] * (1.0f / 104.0f);
}

// ================= conv0 (1->H) + stats =================
__global__ void k_conv0(const float* __restrict__ x, const float* __restrict__ w0, const float* __restrict__ b0,
                        float* __restrict__ y, double* __restrict__ s1g, double* __restrict__ s2g)
{
    int b = blockIdx.x;
    int c = blockIdx.y * 256 + threadIdx.x;
    float w_0 = w0[c * 3 + 0], w_1 = w0[c * 3 + 1], w_2 = w0[c * 3 + 2], bb = b0[c];
    const float* xb = x + b * 104;
    float* yb = y + (long)b * 104 * 512 + c;
    float xm2 = 0.0f, xm1 = 0.0f;
    float s1 = 0.0f, s2 = 0.0f;
    for (int t = 0; t < 104; ++t) {
        float x0 = xb[t];
        float v = w_0 * xm2 + w_1 * xm1 + w_2 * x0 + bb;
        yb[t * 512] = v;
        s1 += v; s2 += v * v;
        xm2 = xm1; xm1 = x0;
    }
    atomicAdd(&s1g[c], (double)s1);
    atomicAdd(&s2g[c], (double)s2);
}

// per-channel scale/shift from fp64 stats
__global__ void k_scaleshift(const double* __restrict__ st, const float* __restrict__ gam,
                             const float* __restrict__ bet, float* __restrict__ sc, float* __restrict__ sh,
                             double invN)
{
    int c = threadIdx.x;
    double m = st[c] * invN;
    double v = st[512 + c] * invN - m * m;
    double rs = 1.0 / sqrt(v + (double)BN_EPS);
    double scale = (double)gam[c] * rs;
    sc[c] = (float)scale;
    sh[c] = (float)((double)bet[c] - m * scale);
}

// transpose conv weights: Wt[tap*512+ci][co] = W[co][ci][tap]
__global__ void k_wt_trans(const float* __restrict__ W, float* __restrict__ Wt)
{
    __shared__ float tile[64 * 196];
    int cib = blockIdx.x, cob = blockIdx.y, tap = blockIdx.z;
    int tid = threadIdx.x;
    for (int it = 0; it < 12; ++it) {
        int s = it * 256 + tid;
        int r = s / 48, c4 = (s % 48) * 4;
        *(float4*)&tile[r * 196 + c4] = *(const float4*)&W[(long)(cob * 64 + r) * 1536 + cib * 192 + c4];
    }
    __syncthreads();
    for (int it = 0; it < 16; ++it) {
        int s = it * 256 + tid;
        int cc = s >> 6, r = s & 63;
        Wt[(long)(tap * 512 + cib * 64 + cc) * 512 + cob * 64 + r] = tile[r * 196 + cc * 3 + tap];
    }
}

// ================= main conv GEMM (H->H, K=3), fused BN+ReLU on input, fused stats =================
__global__ __launch_bounds__(256) void k_conv(
    const float* __restrict__ in, const float* __restrict__ sctab, const float* __restrict__ shtab,
    const float* __restrict__ Wt, const float* __restrict__ bias,
    float* __restrict__ out, double* __restrict__ s1g, double* __restrict__ s2g)
{
    __shared__ float sm[2 * 16 * 132];
    float* As = sm;              // [16 k][132 m]
    float* Bs = sm + 16 * 132;   // [16 k][132 n]
    int tid = threadIdx.x;
    int tx = tid & 15, ty = tid >> 4;
    int m_base = blockIdx.x * 128, co0 = blockIdx.y * 128;
    int mmA[2] = { tid >> 2, (tid >> 2) + 64 };
    int c4A = (tid & 3) * 4;
    long rb[2]; int tv[2];
#pragma unroll
    for (int r = 0; r < 2; ++r) {
        int gr = m_base + mmA[r];
        int bI = gr / 104;
        tv[r] = gr - bI * 104;
        rb[r] = (long)bI * 104;
    }
    float bj[8];
    {
        float4 q0 = *(const float4*)&bias[co0 + tx * 8];
        float4 q1 = *(const float4*)&bias[co0 + tx * 8 + 4];
        bj[0]=q0.x; bj[1]=q0.y; bj[2]=q0.z; bj[3]=q0.w; bj[4]=q1.x; bj[5]=q1.y; bj[6]=q1.z; bj[7]=q1.w;
    }
    float acc[8][8];
#pragma unroll
    for (int i = 0; i < 8; ++i)
#pragma unroll
        for (int j = 0; j < 8; ++j) acc[i][j] = bj[j];

    for (int tap = 0; tap < 3; ++tap) {
        for (int cic = 0; cic < 32; ++cic) {
            int ci0 = cic * 16;
            __syncthreads();
#pragma unroll
            for (int r = 0; r < 2; ++r) {
                int tt = tv[r] + tap - 2;
                float4 v = make_float4(0.f, 0.f, 0.f, 0.f);
                if (tt >= 0) {
                    v = *(const float4*)&in[(rb[r] + tt) * 512 + ci0 + c4A];
                    float4 scv = *(const float4*)&sctab[ci0 + c4A];
                    float4 shv = *(const float4*)&shtab[ci0 + c4A];
                    v.x = fmaxf(fmaf(v.x, scv.x, shv.x), 0.f);
                    v.y = fmaxf(fmaf(v.y, scv.y, shv.y), 0.f);
                    v.z = fmaxf(fmaf(v.z, scv.z, shv.z), 0.f);
                    v.w = fmaxf(fmaf(v.w, scv.w, shv.w), 0.f);
                }
                As[(c4A + 0) * 132 + mmA[r]] = v.x;
                As[(c4A + 1) * 132 + mmA[r]] = v.y;
                As[(c4A + 2) * 132 + mmA[r]] = v.z;
                As[(c4A + 3) * 132 + mmA[r]] = v.w;
            }
#pragma unroll
            for (int it = 0; it < 2; ++it) {
                int s = it * 256 + tid;
                int kk = s >> 5, n4 = (s & 31) * 4;
                *(float4*)&Bs[kk * 132 + n4] =
                    *(const float4*)&Wt[(long)((tap << 9) + ci0 + kk) * 512 + co0 + n4];
            }
            __syncthreads();
#pragma unroll
            for (int kk = 0; kk < 16; ++kk) {
                float4 a0 = *(const float4*)&As[kk * 132 + ty * 8];
                float4 a1 = *(const float4*)&As[kk * 132 + ty * 8 + 4];
                float4 b0 = *(const float4*)&Bs[kk * 132 + tx * 8];
                float4 b1 = *(const float4*)&Bs[kk * 132 + tx * 8 + 4];
                float av[8] = {a0.x,a0.y,a0.z,a0.w,a1.x,a1.y,a1.z,a1.w};
                float bv[8] = {b0.x,b0.y,b0.z,b0.w,b1.x,b1.y,b1.z,b1.w};
#pragma unroll
                for (int i = 0; i < 8; ++i)
#pragma unroll
                    for (int j = 0; j < 8; ++j)
                        acc[i][j] = fmaf(av[i], bv[j], acc[i][j]);
            }
        }
    }
    // write outputs
#pragma unroll
    for (int i = 0; i < 8; ++i) {
        int grow = m_base + ty * 8 + i;
        long base = (long)grow * 512 + co0 + tx * 8;
        *(float4*)&out[base]     = make_float4(acc[i][0], acc[i][1], acc[i][2], acc[i][3]);
        *(float4*)&out[base + 4] = make_float4(acc[i][4], acc[i][5], acc[i][6], acc[i][7]);
    }
    // fused stats
    __syncthreads();
    float* st1 = sm;         // [16][128]
    float* st2 = sm + 2048;
#pragma unroll
    for (int j = 0; j < 8; ++j) {
        float s1 = 0.f, s2 = 0.f;
#pragma unroll
        for (int i = 0; i < 8; ++i) { float v = acc[i][j]; s1 += v; s2 += v * v; }
        st1[ty * 128 + tx * 8 + j] = s1;
        st2[ty * 128 + tx * 8 + j] = s2;
    }
    __syncthreads();
    if (tid < 128) {
        double a = 0.0, b2 = 0.0;
#pragma unroll
        for (int t = 0; t < 16; ++t) { a += st1[t * 128 + tid]; b2 += st2[t * 128 + tid]; }
        atomicAdd(&s1g[co0 + tid], a);
        atomicAdd(&s2g[co0 + tid], b2);
    }
}

// ================= pool: g[b][h] = (1/M) sum_t s[t]*(relu(bn4(y4)) + pe[t][h]) =================
__global__ void k_pool(const float* __restrict__ y4, const float* __restrict__ sctab,
                       const float* __restrict__ shtab, const float* __restrict__ svec,
                       float* __restrict__ g)
{
    __shared__ float sl[104];
    int b = blockIdx.x;
    int c = blockIdx.y * 256 + threadIdx.x;
    if (threadIdx.x < 104) sl[threadIdx.x] = svec[threadIdx.x];
    __syncthreads();
    float sc = sctab[c], sh = shtab[c];
    int he = c & ~1;
    float div = expf((float)he * (-0.017988946039015984f));   // -ln(10000)/512
    float acc = 0.0f;
    const float* yb = y4 + (long)b * 104 * 512 + c;
    for (int t = 0; t < 104; ++t) {
        float v = yb[t * 512];
        float hn = fmaxf(fmaf(v, sc, sh), 0.0f);
        float arg = (float)t * div;
        float pe = (c & 1) ? cosf(arg) : sinf(arg);
        acc += sl[t] * (hn + pe);
    }
    g[(long)b * 512 + c] = acc * (1.0f / 104.0f);
}

// ================= 512x512 transpose =================
__global__ void k_t512(const float* __restrict__ in, float* __restrict__ outp)
{
    __shared__ float tile[64 * 68];
    int bx = blockIdx.x, by = blockIdx.y;
    int tid = threadIdx.x;
    for (int it = 0; it < 4; ++it) {
        int s = it * 256 + tid;
        int r = s >> 4, c4 = (s & 15) * 4;
        *(float4*)&tile[r * 68 + c4] = *(const float4*)&in[(long)(bx * 64 + r) * 512 + by * 64 + c4];
    }
    __syncthreads();
    for (int it = 0; it < 4; ++it) {
        int s = it * 256 + tid;
        int r = s >> 4, c4 = (s & 15) * 4;
        float4 v;
        v.x = tile[(c4 + 0) * 68 + r];
        v.y = tile[(c4 + 1) * 68 + r];
        v.z = tile[(c4 + 2) * 68 + r];
        v.w = tile[(c4 + 3) * 68 + r];
        *(float4*)&outp[(long)(by * 64 + r) * 512 + bx * 64 + c4] = v;
    }
}

// fc-stage batch stats
__global__ void k_fcstats(const float* __restrict__ Z, double* __restrict__ s1g, double* __restrict__ s2g)
{
    int strip = blockIdx.x >> 1, half = blockIdx.x & 1;
    int o = half * 256 + threadIdx.x;
    float s1 = 0.f, s2 = 0.f;
    for (int b = strip * 64; b < strip * 64 + 64; ++b) {
        float v = Z[(long)b * 512 + o];
        s1 += v; s2 += v * v;
    }
    atomicAdd(&s1g[o], (double)s1);
    atomicAdd(&s2g[o], (double)s2);
}

// BN(batch) -> exact GELU -> fc2
__global__ __launch_bounds__(256) void k_final(const float* __restrict__ zin, const double* __restrict__ st,
                                               const float* __restrict__ gam, const float* __restrict__ bet,
                                               const float* __restrict__ w2, const float* __restrict__ b2,
                                               float* __restrict__ outp)
{
    __shared__ float red[256];
    int b = blockIdx.x, tid = threadIdx.x;
    int oo[2] = { tid, tid + 256 };
    float gv[2];
#pragma unroll
    for (int q = 0; q < 2; ++q) {
        int o = oo[q];
        double m = st[o] * (1.0 / 512.0);
        double var = st[512 + o] * (1.0 / 512.0) - m * m;
        double rs = 1.0 / sqrt(var + (double)BN_EPS);
        float xn = (float)(((double)zin[(long)b * 512 + o] - m) * rs * (double)gam[o] + (double)bet[o]);
        gv[q] = 0.5f * xn * (1.0f + erff(xn * 0.70710678118654752f));
    }
    for (int n = 0; n < 5; ++n) {
        float p = gv[0] * w2[n * 512 + oo[0]] + gv[1] * w2[n * 512 + oo[1]];
        red[tid] = p;
        __syncthreads();
        for (int off = 128; off; off >>= 1) { if (tid < off) red[tid] += red[tid + off]; __syncthreads(); }
        if (tid == 0) outp[b * 5 + n] = red[0] + b2[n];
        __syncthreads();
    }
}

// ===================== host side =====================
static void mm(hipStream_t s, int Mt, int Nt, int z,
               const float* A, long sA, int lda,
               const float* B, long sB, int ldb,
               float* C, long sC, int ldc,
               int K, int mode, float alpha, float beta,
               const float* aux, long sAux, const float* aux2, int pc, int pr)
{
    dim3 g(Mt, Nt, z);
    k_mm<<<g, 256, 0, s>>>(A, sA, lda, B, sB, ldb, C, sC, ldc, K, mode, alpha, beta, aux, sAux, aux2, pc, pr);
}

extern "C" void kernel_launch(void* const* d_in, const int* in_sizes, int n_in,
                              void* d_out, int out_size, void* d_ws, size_t ws_size,
                              hipStream_t stream)
{
    (void)in_sizes; (void)n_in; (void)out_size;
    const float* x       = (const float*)d_in[0];
    const float* conv_w0 = (const float*)d_in[1];
    const float* conv_b0 = (const float*)d_in[2];
    const float* conv_w  = (const float*)d_in[3];
    const float* conv_b  = (const float*)d_in[4];
    const float* bn_g    = (const float*)d_in[5];
    const float* bn_b    = (const float*)d_in[6];
    const float* proj_w  = (const float*)d_in[7];
    const float* proj_b  = (const float*)d_in[8];
    const float* A_all   = (const float*)d_in[9];
    const float* B_all   = (const float*)d_in[10];
    const float* C_all   = (const float*)d_in[11];
    const float* fc1_w   = (const float*)d_in[12];
    const float* fc1_b   = (const float*)d_in[13];
    const float* fbn_g   = (const float*)d_in[14];
    const float* fbn_b   = (const float*)d_in[15];
    const float* fc2_w   = (const float*)d_in[16];
    const float* fc2_b   = (const float*)d_in[17];
    float* outp = (float*)d_out;
    char* ws = (char*)d_ws;
    if (ws_size < WS_NEED) { printf("ws too small: %zu < %zu\n", ws_size, WS_NEED); return; }

    float* act0 = (float*)(ws + OFF_ACT0);
    float* act1 = (float*)(ws + OFF_ACT1);
    float* Xb   = (float*)(ws + OFF_X);
    float* T1   = (float*)(ws + OFF_T1);
    float* T2   = (float*)(ws + OFF_T2);
    float* Eb   = (float*)(ws + OFF_E);
    float* MW   = (float*)(ws + OFF_MW);
    float* ROWT = (float*)(ws + OFF_ROWT);
    float* COLS = (float*)(ws + OFF_COLS);
    float* PIVI = (float*)(ws + OFF_PIVI);
    float* WT   = (float*)(ws + OFF_WT);
    float* PJT  = (float*)(ws + OFF_PJT);
    float* F1T  = (float*)(ws + OFF_F1T);
    float* G    = (float*)(ws + OFF_G);
    float* POOL = (float*)(ws + OFF_POOL);
    float* Zb   = (float*)(ws + OFF_Z);
    double* ST  = (double*)(ws + OFF_ST);
    float* SC   = (float*)(ws + OFF_SC);
    float* U    = (float*)(ws + OFF_U);
    float* SV   = (float*)(ws + OFF_SV);
    float* V    = (float*)(ws + OFF_V);
    float* WV   = (float*)(ws + OFF_WV);
    float* TRM  = (float*)(ws + OFF_TRM);
    float* SVEC = (float*)(ws + OFF_S);

    const long SM = 262144;   // per-z matrix stride (floats)
    hipMemsetAsync(ws + OFF_ST, 0, 49152, stream);

    // ---- ZOH: expm Taylor (order 4, Horner) ----
    k_build<<<5120, 256, 0, stream>>>(A_all, Xb, MW);
    mm(stream, 8, 8, 5, Xb, SM, 512, Xb, SM, 512, T1, SM, 512, 512, 2, 1.0f/12.0f, 1.0f/3.0f, Xb, SM, nullptr, 0, 0);
    mm(stream, 8, 8, 5, Xb, SM, 512, T1, SM, 512, T2, SM, 512, 512, 2, 0.5f, 0.5f, Xb, SM, nullptr, 0, 0);
    mm(stream, 8, 8, 5, Xb, SM, 512, T2, SM, 512, Eb, SM, 512, 512, 2, 1.0f, 1.0f, Xb, SM, nullptr, 0, 0);
    // A2 = E*E + 2E + I (into Xb), A4 (into T1), A8 (into T2)
    mm(stream, 8, 8, 5, Eb, SM, 512, Eb, SM, 512, Xb, SM, 512, 512, 1, 1.0f, 0.0f, Eb, SM, nullptr, 0, 0);
    mm(stream, 8, 8, 5, Xb, SM, 512, Xb, SM, 512, T1, SM, 512, 512, 0, 1.0f, 0.0f, nullptr, 0, nullptr, 0, 0);
    mm(stream, 8, 8, 5, T1, SM, 512, T1, SM, 512, T2, SM, 512, 512, 0, 1.0f, 0.0f, nullptr, 0, nullptr, 0, 0);
    // ---- blocked Gauss-Jordan sweep inverse of S (MW -> inv(S)) ----
    for (int p = 0; p < 8; ++p) {
        int pc = p * 64;
        k_copycol<<<640, 256, 0, stream>>>(MW, COLS, pc);
        k_inv64<<<5, 256, 0, stream>>>(MW, p, PIVI);
        mm(stream, 1, 8, 5, PIVI, 4096, 64, MW + pc * 512, SM, 512, ROWT, 32768, 512, 64, 3, 1.0f, 0.0f, PIVI, 4096, nullptr, pc, pc);
        mm(stream, 8, 8, 5, COLS, 32768, 64, ROWT, 32768, 512, MW, SM, 512, 64, 4, 1.0f, 0.0f, nullptr, 0, nullptr, pc, pc);
        k_copyrow<<<640, 256, 0, stream>>>(MW, ROWT, pc);
    }
    // ---- B_bar with one fp64-residual refinement step ----
    k_matvecA<<<dim3(512, 5), 64, 0, stream>>>(Eb, SM, B_all, 512, U, 512, nullptr, 0, 0.1f, 0.0f, 0);   // u = 0.1*(E*Bv)
    k_matvecA<<<dim3(512, 5), 64, 0, stream>>>(MW, SM, U, 512, V, 4096, nullptr, 0, 1.0f, 0.0f, 0);      // V0 = inv(S)*u
    k_matvecA<<<dim3(512, 5), 64, 0, stream>>>(A_all, SM, V, 4096, SV, 512, U, 512, 1.0f, 0.001f, 0);    // r = u - S*V0
    k_matvecA<<<dim3(512, 5), 64, 0, stream>>>(MW, SM, SV, 512, V, 4096, nullptr, 0, 1.0f, 0.0f, 1);     // V0 += inv(S)*r
    // ---- Krylov: V_{j+1} = (I+E) V_j ; W_{j+1} = W_j * A8 ----
    for (int j = 0; j < 7; ++j)
        k_matvecA<<<dim3(512, 5), 64, 0, stream>>>(Eb, SM, V + j * 512, 4096, V + (j + 1) * 512, 4096, nullptr, 0, 1.0f, 1.0f, 0);
    k_copyW0<<<10, 256, 0, stream>>>(C_all, WV);
    for (int j = 0; j < 12; ++j)
        k_matvecT<<<5, 512, 0, stream>>>(T2, SM, WV + j * 512, 6656, WV + (j + 1) * 512, 6656);
    k_terms<<<5, 256, 0, stream>>>(WV, V, TRM);
    k_skernel<<<1, 128, 0, stream>>>(TRM, SVEC);

    // ---- conv chain ----
    k_conv0<<<dim3(512, 2), 256, 0, stream>>>(x, conv_w0, conv_b0, act0, ST, ST + 512);
    k_scaleshift<<<1, 512, 0, stream>>>(ST, bn_g, bn_b, SC, SC + 512, 1.0 / (double)BM);
    for (int l = 1; l <= 4; ++l) {
        const float* Win = conv_w + (size_t)(l - 1) * 512 * 512 * 3;
        k_wt_trans<<<dim3(8, 8, 3), 256, 0, stream>>>(Win, WT);
        const float* inb = (l & 1) ? act0 : act1;
        float* outb      = (l & 1) ? act1 : act0;
        k_conv<<<dim3(416, 4), 256, 0, stream>>>(inb, SC + (l - 1) * 1024, SC + (l - 1) * 1024 + 512,
                                                 WT, conv_b + (l - 1) * 512, outb,
                                                 ST + l * 1024, ST + l * 1024 + 512);
        k_scaleshift<<<1, 512, 0, stream>>>(ST + l * 1024, bn_g + l * 512, bn_b + l * 512,
                                            SC + l * 1024, SC + l * 1024 + 512, 1.0 / (double)BM);
    }
    // y4 lives in act0 (l=4 writes act0)
    k_pool<<<dim3(512, 2), 256, 0, stream>>>(act0, SC + 4 * 1024, SC + 4 * 1024 + 512, SVEC, G);

    // ---- head ----
    k_t512<<<dim3(8, 8), 256, 0, stream>>>(proj_w, PJT);
    k_t512<<<dim3(8, 8), 256, 0, stream>>>(fc1_w, F1T);
    mm(stream, 8, 8, 1, G, 0, 512, PJT, 0, 512, POOL, 0, 512, 512, 5, 1.0f, 0.0f, proj_b, 0, SVEC + 104, 0, 0);
    mm(stream, 8, 8, 1, POOL, 0, 512, F1T, 0, 512, Zb, 0, 512, 512, 6, 1.0f, 0.0f, fc1_b, 0, nullptr, 0, 0);
    k_fcstats<<<16, 256, 0, stream>>>(Zb, ST + 5 * 1024, ST + 5 * 1024 + 512);
    k_final<<<512, 256, 0, stream>>>(Zb, ST + 5 * 1024, fbn_g, fbn_b, fc2_w, fc2_b, outp);
}

// Round 2
// 2497.207 us; speedup vs baseline: 2.6944x; 2.6944x over previous
//
#include <hip/hip_runtime.h>
#include <cstdio>
#include <cmath>
#include <cstdint>

// ---------------- problem constants ----------------
constexpr int HH = 512;      // hidden
constexpr int MM_T = 104;    // timesteps
constexpr int BB = 512;      // batch
constexpr int BM = BB * MM_T;       // 53248 rows
constexpr float BN_EPS = 1e-5f;

// ---------------- workspace layout (bytes) ----------------
constexpr size_t SZ_BF   = (size_t)BM * HH * 2;            // 54,525,952
constexpr size_t SZ_MAT5 = (size_t)5 * 512 * 512 * 4;      // 5,242,880
constexpr size_t OFF_YBF = 0;                              // raw conv out, bf16
constexpr size_t OFF_ABF = OFF_YBF + SZ_BF;                // BN+ReLU activations, bf16
constexpr size_t OFF_WT2 = OFF_ABF + SZ_BF;                // conv weights [4][3][co][ci] bf16
constexpr size_t OFF_ZP  = OFF_WT2 + 6291456;              // zero page (256 B)
constexpr size_t OFF_X   = OFF_ZP  + 256;                  // X = 0.1*A  -> later A2
constexpr size_t OFF_T1  = OFF_X   + SZ_MAT5;              // temp -> later A4
constexpr size_t OFF_T2  = OFF_T1  + SZ_MAT5;              // temp -> later A8
constexpr size_t OFF_E   = OFF_T2  + SZ_MAT5;              // E = expm(0.1A) - I
constexpr size_t OFF_MW  = OFF_E   + SZ_MAT5;              // S -> becomes inv(S)
constexpr size_t OFF_ROWT= OFF_MW  + SZ_MAT5;              // [5][64][512]
constexpr size_t OFF_COLS= OFF_ROWT + 655360;              // [5][512][64]
constexpr size_t OFF_PIVI= OFF_COLS + 655360;              // [5][64][64]
constexpr size_t OFF_PJT = OFF_PIVI + 81920;               // proj_w^T
constexpr size_t OFF_F1T = OFF_PJT + 1048576;              // fc1_w^T
constexpr size_t OFF_G   = OFF_F1T + 1048576;              // g[b][h]
constexpr size_t OFF_POOL= OFF_G   + 1048576;              // pooled[b][o]
constexpr size_t OFF_Z   = OFF_POOL + 1048576;             // fc1 out
constexpr size_t OFF_ST  = OFF_Z   + 1048576;              // fp64 stats [6][2][512]
constexpr size_t OFF_SC  = OFF_ST  + 49152;                // scale/shift [5][2][512] f32
constexpr size_t OFF_U   = OFF_SC  + 20480;                // u[5][512]
constexpr size_t OFF_SV  = OFF_U   + 10240;                // residual r[5][512]
constexpr size_t OFF_V   = OFF_SV  + 10240;                // V[5][8][512]
constexpr size_t OFF_WV  = OFF_V   + 81920;                // W[5][13][512]
constexpr size_t OFF_TRM = OFF_WV  + 133120;               // terms[5][104]
constexpr size_t OFF_S   = OFF_TRM + 2304;                 // s[104] + sbar
constexpr size_t WS_NEED = OFF_S + 512;

// ---------------- bf16 helpers ----------------
__device__ __forceinline__ float bf2f(unsigned short u) {
    union { uint32_t i; float f; } x; x.i = (uint32_t)u << 16; return x.f;
}
__device__ __forceinline__ unsigned short f2bf(float f) {
    union { float f; uint32_t i; } x; x.f = f;
    uint32_t r = x.i + 0x7FFFu + ((x.i >> 16) & 1u);
    return (unsigned short)(r >> 16);
}

typedef __bf16 bf16x8 __attribute__((ext_vector_type(8)));
typedef float  f32x4  __attribute__((ext_vector_type(4)));

__device__ __forceinline__ void gld16(const void* g, void* l) {
    __builtin_amdgcn_global_load_lds((const __attribute__((address_space(1))) uint32_t*)g,
                                     (__attribute__((address_space(3))) uint32_t*)l, 16, 0, 0);
}

// ================= ZOH: build X = 0.1*A, S = A + 0.001 I =================
__global__ void k_build(const float* __restrict__ Aall, float* __restrict__ X, float* __restrict__ MW)
{
    long i = (long)blockIdx.x * 256 + threadIdx.x;     // 5*262144 total
    float a = Aall[i];
    X[i] = 0.1f * a;
    int rc = (int)(i & 262143);
    int r = rc >> 9, c = rc & 511;
    MW[i] = a + ((r == c) ? 0.001f : 0.0f);
}

// ================= generic batched 64x64-tile fp32 matmul =================
__global__ __launch_bounds__(256) void k_mm(
    const float* __restrict__ A, long sA, int lda,
    const float* __restrict__ Bm, long sB, int ldb,
    float* __restrict__ C, long sC, int ldc,
    int K, int mode, float alpha, float beta,
    const float* __restrict__ aux, long sAux,
    const float* __restrict__ aux2, int pc, int pr)
{
    __shared__ float sm[2 * 32 * 68];
    float* As = sm;
    float* Bs = sm + 32 * 68;
    int z = blockIdx.z;
    A  += (long)z * sA;
    Bm += (long)z * sB;
    C  += (long)z * sC;
    if (aux) aux += (long)z * sAux;
    int m0 = blockIdx.x * 64, n0 = blockIdx.y * 64;
    if (mode == 4 && m0 == pr) return;
    int tid = threadIdx.x;
    int tx = tid & 15, ty = tid >> 4;
    float acc[4][4] = {};
    for (int k0 = 0; k0 < K; k0 += 32) {
        __syncthreads();
#pragma unroll
        for (int it = 0; it < 2; ++it) {
            int s = it * 256 + tid;
            int mm = s >> 3, k4 = (s & 7) * 4;
            float4 v = *(const float4*)&A[(long)(m0 + mm) * lda + k0 + k4];
            As[(k4 + 0) * 68 + mm] = v.x;
            As[(k4 + 1) * 68 + mm] = v.y;
            As[(k4 + 2) * 68 + mm] = v.z;
            As[(k4 + 3) * 68 + mm] = v.w;
        }
#pragma unroll
        for (int it = 0; it < 2; ++it) {
            int s = it * 256 + tid;
            int kk = s >> 4, n4 = (s & 15) * 4;
            *(float4*)&Bs[kk * 68 + n4] = *(const float4*)&Bm[(long)(k0 + kk) * ldb + n0 + n4];
        }
        __syncthreads();
#pragma unroll 8
        for (int kk = 0; kk < 32; ++kk) {
            float4 a = *(const float4*)&As[kk * 68 + ty * 4];
            float4 b = *(const float4*)&Bs[kk * 68 + tx * 4];
            float av[4] = {a.x, a.y, a.z, a.w};
            float bv[4] = {b.x, b.y, b.z, b.w};
#pragma unroll
            for (int i = 0; i < 4; ++i)
#pragma unroll
                for (int j = 0; j < 4; ++j)
                    acc[i][j] = fmaf(av[i], bv[j], acc[i][j]);
        }
    }
    float sc2 = (mode == 5) ? aux2[0] : 0.0f;
#pragma unroll
    for (int i = 0; i < 4; ++i) {
        int row = m0 + ty * 4 + i;
        int col0 = n0 + tx * 4;
        long base = (long)row * ldc + col0;
        float v[4];
#pragma unroll
        for (int j = 0; j < 4; ++j) v[j] = acc[i][j];
        if (mode == 0) {
            for (int j = 0; j < 4; ++j) v[j] *= alpha;
        } else if (mode == 1) {
            for (int j = 0; j < 4; ++j) {
                int col = col0 + j;
                v[j] = v[j] + 2.0f * aux[(long)row * 512 + col] + ((row == col) ? 1.0f : 0.0f);
            }
        } else if (mode == 2) {
            for (int j = 0; j < 4; ++j)
                v[j] = alpha * v[j] + beta * aux[(long)row * 512 + col0 + j];
        } else if (mode == 3) {
            bool inP = (col0 >= pc && col0 < pc + 64);
            if (inP)
                for (int j = 0; j < 4; ++j) v[j] = aux[row * 64 + (col0 + j - pc)];
        } else if (mode == 4) {
            bool inP = (col0 >= pc && col0 < pc + 64);
            float4 oldv = *(const float4*)&C[base];
            float ov[4] = {oldv.x, oldv.y, oldv.z, oldv.w};
            for (int j = 0; j < 4; ++j) v[j] = (inP ? 0.0f : ov[j]) - v[j];
        } else if (mode == 5) {
            for (int j = 0; j < 4; ++j) v[j] += aux[col0 + j] * sc2;
        } else if (mode == 6) {
            for (int j = 0; j < 4; ++j) v[j] += aux[col0 + j];
        }
        *(float4*)&C[base] = make_float4(v[0], v[1], v[2], v[3]);
    }
}

// ================= pivoted 64x64 Gauss-Jordan inverse in LDS =================
__global__ __launch_bounds__(256) void k_inv64(float* __restrict__ MW, int pblk, float* __restrict__ PIVI)
{
    __shared__ float mat[64][65];
    __shared__ int perm[64];
    __shared__ int pividx;
    int z = blockIdx.x;
    float* Mg = MW + (long)z * 262144 + (long)pblk * 64 * 512 + pblk * 64;
    int tid = threadIdx.x;
    for (int it = 0; it < 16; ++it) {
        int idx = it * 256 + tid;
        int r = idx >> 6, c = idx & 63;
        mat[r][c] = Mg[r * 512 + c];
    }
    __syncthreads();
    for (int j = 0; j < 64; ++j) {
        if (tid == 0) {
            int best = j; float bv = fabsf(mat[j][j]);
            for (int i = j + 1; i < 64; ++i) {
                float a = fabsf(mat[i][j]);
                if (a > bv) { bv = a; best = i; }
            }
            perm[j] = best; pividx = best;
        }
        __syncthreads();
        int r = pividx;
        if (r != j && tid < 64) {
            float t = mat[j][tid]; mat[j][tid] = mat[r][tid]; mat[r][tid] = t;
        }
        __syncthreads();
        float pv = mat[j][j];
        __syncthreads();
        float d = 1.0f / pv;
        if (tid < 64) mat[j][tid] = (tid == j) ? d : mat[j][tid] * d;
        __syncthreads();
        __shared__ float fv[64];
        if (tid < 64) fv[tid] = mat[tid][j];
        __syncthreads();
        {
            int i = tid & 63, cc = tid >> 6;
            if (i != j) {
                float f = fv[i];
#pragma unroll
                for (int c0 = 0; c0 < 16; ++c0) {
                    int c = cc * 16 + c0;
                    float val = mat[i][c] - f * mat[j][c];
                    if (c == j) val = -f * d;
                    mat[i][c] = val;
                }
            }
        }
        __syncthreads();
    }
    for (int j = 63; j >= 0; --j) {
        int r = perm[j];
        if (r != j && tid < 64) {
            float t = mat[tid][j]; mat[tid][j] = mat[tid][r]; mat[tid][r] = t;
        }
        __syncthreads();
    }
    float* Pg = PIVI + z * 4096;
    for (int it = 0; it < 16; ++it) {
        int idx = it * 256 + tid;
        int r = idx >> 6, c = idx & 63;
        Pg[r * 64 + c] = mat[r][c];
    }
}

__global__ void k_copycol(const float* __restrict__ MW, float* __restrict__ COLS, int pc)
{
    int idx = blockIdx.x * 256 + threadIdx.x;   // 163840
    int z = idx >> 15, rem = idx & 32767;
    int i = rem >> 6, c = rem & 63;
    COLS[idx] = MW[(long)z * 262144 + (long)i * 512 + pc + c];
}
__global__ void k_copyrow(float* __restrict__ MW, const float* __restrict__ ROWT, int pr)
{
    int idx = blockIdx.x * 256 + threadIdx.x;   // 163840
    int z = idx >> 15, rem = idx & 32767;
    int r = rem >> 9, c = rem & 511;
    MW[(long)z * 262144 + (long)(pr + r) * 512 + c] = ROWT[idx];
}
__global__ void k_copyW0(const float* __restrict__ Call, float* __restrict__ WV)
{
    int idx = blockIdx.x * 256 + threadIdx.x;   // 2560
    int z = idx >> 9, i = idx & 511;
    WV[z * 6656 + i] = Call[idx];
}

// ================= batched matvec: y = alpha*(A x) + beta*x  (variants) =================
__global__ void k_matvecA(const float* __restrict__ A, long sA,
                          const float* __restrict__ x, long sx,
                          float* __restrict__ y, long sy,
                          const float* __restrict__ sub, long ssub,
                          float alpha, float beta, int accum)
{
    int row = blockIdx.x, z = blockIdx.y, lane = threadIdx.x;
    A += (long)z * sA; x += (long)z * sx; y += (long)z * sy;
    if (sub) sub += (long)z * ssub;
    const float* ar = A + (long)row * 512;
    double acc = 0.0;
#pragma unroll
    for (int m = 0; m < 8; ++m) {
        int k = lane + m * 64;
        acc += (double)ar[k] * (double)x[k];
    }
    for (int off = 32; off; off >>= 1) acc += __shfl_down(acc, off);
    if (lane == 0) {
        float val = alpha * (float)acc + beta * x[row];
        if (sub) val = sub[row] - val;
        if (accum) y[row] += val; else y[row] = val;
    }
}

// w' = w^T * A8   (coalesced over output index)
__global__ __launch_bounds__(512) void k_matvecT(const float* __restrict__ A8, long sA,
                                                 const float* __restrict__ win, long swin,
                                                 float* __restrict__ wout, long swout)
{
    __shared__ float wl[512];
    int z = blockIdx.x, tid = threadIdx.x;
    A8 += (long)z * sA;
    wl[tid] = win[(long)z * swin + tid];
    __syncthreads();
    double acc = 0.0;
#pragma unroll 8
    for (int j = 0; j < 512; ++j)
        acc += (double)A8[(long)j * 512 + tid] * (double)wl[j];
    wout[(long)z * swout + tid] = (float)acc;
}

// terms[z][8j+i] = W[z][j] . V[z][i]
__global__ void k_terms(const float* __restrict__ WV, const float* __restrict__ V, float* __restrict__ terms)
{
    int z = blockIdx.x, tid = threadIdx.x;
    int lane = tid & 63, wv = tid >> 6;
    for (int d = wv; d < 104; d += 4) {
        int j = d >> 3, i = d & 7;
        const float* wp = WV + z * 6656 + j * 512;
        const float* vp = V + z * 4096 + i * 512;
        float acc = 0.0f;
#pragma unroll
        for (int m = 0; m < 8; ++m) {
            int k = lane + m * 64;
            acc += wp[k] * vp[k];
        }
        for (int off = 32; off; off >>= 1) acc += __shfl_down(acc, off);
        if (lane == 0) terms[z * 104 + d] = acc;
    }
}

// s[t] = prod_l flip(terms_l)[t]/(||terms_l||+1e-6);  s[104] = mean_t s[t]
__global__ __launch_bounds__(128) void k_skernel(const float* __restrict__ terms, float* __restrict__ svec)
{
    __shared__ float red[128];
    __shared__ float invn[5];
    int tid = threadIdx.x;
    for (int l = 0; l < 5; ++l) {
        float v = (tid < 104) ? terms[l * 104 + tid] : 0.0f;
        red[tid] = v * v;
        __syncthreads();
        for (int off = 64; off; off >>= 1) { if (tid < off) red[tid] += red[tid + off]; __syncthreads(); }
        if (tid == 0) invn[l] = 1.0f / (sqrtf(red[0]) + 1e-6f);
        __syncthreads();
    }
    float s = 0.0f;
    if (tid < 104) {
        s = 1.0f;
        for (int l = 0; l < 5; ++l) s *= terms[l * 104 + (103 - tid)] * invn[l];
        svec[tid] = s;
    }
    red[tid] = (tid < 104) ? s : 0.0f;
    __syncthreads();
    for (int off = 64; off; off >>= 1) { if (tid < off) red[tid] += red[tid + off]; __syncthreads(); }
    if (tid == 0) svec[104] = red[0] * (1.0f / 104.0f);
}

// ================= conv0 (1->H) + stats, bf16 out =================
__global__ void k_conv0(const float* __restrict__ x, const float* __restrict__ w0, const float* __restrict__ b0,
                        unsigned short* __restrict__ y, double* __restrict__ s1g, double* __restrict__ s2g)
{
    int b = blockIdx.x;
    int c = blockIdx.y * 256 + threadIdx.x;
    float w_0 = w0[c * 3 + 0], w_1 = w0[c * 3 + 1], w_2 = w0[c * 3 + 2], bb = b0[c];
    const float* xb = x + b * 104;
    unsigned short* yb = y + (long)b * 104 * 512 + c;
    float xm2 = 0.0f, xm1 = 0.0f;
    float s1 = 0.0f, s2 = 0.0f;
    for (int t = 0; t < 104; ++t) {
        float x0 = xb[t];
        float v = w_0 * xm2 + w_1 * xm1 + w_2 * x0 + bb;
        yb[t * 512] = f2bf(v);
        s1 += v; s2 += v * v;
        xm2 = xm1; xm1 = x0;
    }
    atomicAdd(&s1g[c], (double)s1);
    atomicAdd(&s2g[c], (double)s2);
}

// per-channel scale/shift from fp64 stats
__global__ void k_scaleshift(const double* __restrict__ st, const float* __restrict__ gam,
                             const float* __restrict__ bet, float* __restrict__ sc, float* __restrict__ sh,
                             double invN)
{
    int c = threadIdx.x;
    double m = st[c] * invN;
    double v = st[512 + c] * invN - m * m;
    double rs = 1.0 / sqrt(v + (double)BN_EPS);
    double scale = (double)gam[c] * rs;
    sc[c] = (float)scale;
    sh[c] = (float)((double)bet[c] - m * scale);
}

// conv weights -> bf16 [l][tap][co][ci]
__global__ void k_wt2(const float* __restrict__ W, unsigned short* __restrict__ Wt2)
{
    int co = blockIdx.x, l = blockIdx.y, tid = threadIdx.x;
    const float* src = W + (long)(l * 512 + co) * 512 * 3;
    unsigned short* dst = Wt2 + (long)l * 3 * 262144 + ((long)co << 9);
#pragma unroll
    for (int q = 0; q < 2; ++q) {
        int ci = tid * 2 + q;
        float f0 = src[ci * 3 + 0], f1 = src[ci * 3 + 1], f2 = src[ci * 3 + 2];
        dst[ci] = f2bf(f0);
        dst[262144 + ci] = f2bf(f1);
        dst[524288 + ci] = f2bf(f2);
    }
}

// BN+ReLU elementwise: act = max(sc*y+sh, 0), bf16 in/out
__global__ __launch_bounds__(256) void k_bnrelu(const unsigned short* __restrict__ y,
                                                const float* __restrict__ sc, const float* __restrict__ sh,
                                                unsigned short* __restrict__ a)
{
    long idx = (long)blockIdx.x * 256 + threadIdx.x;
    long e = idx * 8;
    int c0 = (int)(e & 511);
    uint4 v = *(const uint4*)(y + e);
    float4 s0 = *(const float4*)(sc + c0);
    float4 s1 = *(const float4*)(sc + c0 + 4);
    float4 h0 = *(const float4*)(sh + c0);
    float4 h1 = *(const float4*)(sh + c0 + 4);
    unsigned short u[8];
    u[0] = (unsigned short)(v.x & 0xFFFF); u[1] = (unsigned short)(v.x >> 16);
    u[2] = (unsigned short)(v.y & 0xFFFF); u[3] = (unsigned short)(v.y >> 16);
    u[4] = (unsigned short)(v.z & 0xFFFF); u[5] = (unsigned short)(v.z >> 16);
    u[6] = (unsigned short)(v.w & 0xFFFF); u[7] = (unsigned short)(v.w >> 16);
    float ss[8] = {s0.x, s0.y, s0.z, s0.w, s1.x, s1.y, s1.z, s1.w};
    float hh[8] = {h0.x, h0.y, h0.z, h0.w, h1.x, h1.y, h1.z, h1.w};
    unsigned short o[8];
#pragma unroll
    for (int j = 0; j < 8; ++j) {
        float f = fmaxf(fmaf(bf2f(u[j]), ss[j], hh[j]), 0.0f);
        o[j] = f2bf(f);
    }
    uint4 w;
    w.x = (uint32_t)o[0] | ((uint32_t)o[1] << 16);
    w.y = (uint32_t)o[2] | ((uint32_t)o[3] << 16);
    w.z = (uint32_t)o[4] | ((uint32_t)o[5] << 16);
    w.w = (uint32_t)o[6] | ((uint32_t)o[7] << 16);
    *(uint4*)(a + e) = w;
}

// ================= MFMA conv GEMM (H->H, K=3 taps x 512) =================
// A = act_bf [BM][512] (BN+ReLU'd), B = Wt2 [tap][co][ci], C += bias; out bf16 + fp64 stats.
__global__ __launch_bounds__(256) void k_convm(
    const unsigned short* __restrict__ act,
    const unsigned short* __restrict__ Wt2,
    const float* __restrict__ bias,
    const unsigned short* __restrict__ zp,
    unsigned short* __restrict__ yout,
    double* __restrict__ s1g, double* __restrict__ s2g)
{
    __shared__ __align__(16) unsigned short As[128 * 32];
    __shared__ __align__(16) unsigned short Bs[128 * 32];
    int tid = threadIdx.x;
    int m0 = blockIdx.x * 128, co0 = blockIdx.y * 128;
    // staging: thread -> row tid>>2 (and +64), 8 elems at (tid&3)*8
    int arow = tid >> 2;
    int aci  = (tid & 3) * 8;
    int gr0 = m0 + arow, gr1 = gr0 + 64;
    int b0 = gr0 / 104, t0 = gr0 - b0 * 104;
    int b1 = gr1 / 104, t1 = gr1 - b1 * 104;
    int w = tid >> 6, lane = tid & 63;
    int wr = (w >> 1) * 64;        // wave row offset in tile
    int wc = (w & 1) * 64;         // wave col offset in tile
    int fr = lane & 15;            // fragment row/col index
    int fkb = (lane >> 4) * 8;     // fragment k offset (elems)
    int quad = lane >> 4;

    f32x4 zero = {0.f, 0.f, 0.f, 0.f};
    f32x4 acc[4][4];
#pragma unroll
    for (int i = 0; i < 4; ++i)
#pragma unroll
        for (int j = 0; j < 4; ++j) acc[i][j] = zero;

    for (int tap = 0; tap < 3; ++tap) {
        int tt0 = t0 + tap - 2, tt1 = t1 + tap - 2;
        const unsigned short* pr0 = (tt0 >= 0) ? act + ((long)(b0 * 104 + tt0) << 9) + aci : nullptr;
        const unsigned short* pr1 = (tt1 >= 0) ? act + ((long)(b1 * 104 + tt1) << 9) + aci : nullptr;
        const unsigned short* wB0 = Wt2 + ((long)tap << 18) + ((long)(co0 + arow) << 9) + aci;
        const unsigned short* wB1 = wB0 + (64 << 9);
#pragma unroll 1
        for (int s = 0; s < 16; ++s) {
            int ci0 = s * 32;
            __syncthreads();
            gld16(pr0 ? pr0 + ci0 : zp + aci, &As[tid * 8]);
            gld16(pr1 ? pr1 + ci0 : zp + aci, &As[2048 + tid * 8]);
            gld16(wB0 + ci0, &Bs[tid * 8]);
            gld16(wB1 + ci0, &Bs[2048 + tid * 8]);
            __syncthreads();
            bf16x8 af[4], bfr[4];
#pragma unroll
            for (int i = 0; i < 4; ++i)
                af[i] = *(const bf16x8*)&As[(wr + i * 16 + fr) * 32 + fkb];
#pragma unroll
            for (int j = 0; j < 4; ++j)
                bfr[j] = *(const bf16x8*)&Bs[(wc + j * 16 + fr) * 32 + fkb];
#pragma unroll
            for (int i = 0; i < 4; ++i)
#pragma unroll
                for (int j = 0; j < 4; ++j)
                    acc[i][j] = __builtin_amdgcn_mfma_f32_16x16x32_bf16(af[i], bfr[j], acc[i][j], 0, 0, 0);
        }
    }
    // epilogue: bias, bf16 store, per-channel stats
    float bcol[4], s1[4] = {0, 0, 0, 0}, s2[4] = {0, 0, 0, 0};
#pragma unroll
    for (int jt = 0; jt < 4; ++jt) bcol[jt] = bias[co0 + wc + jt * 16 + fr];
#pragma unroll
    for (int i = 0; i < 4; ++i) {
        int rbase = m0 + wr + i * 16 + quad * 4;
#pragma unroll
        for (int jt = 0; jt < 4; ++jt) {
            int col = co0 + wc + jt * 16 + fr;
#pragma unroll
            for (int r = 0; r < 4; ++r) {
                float v = acc[i][jt][r] + bcol[jt];
                yout[(long)(rbase + r) * 512 + col] = f2bf(v);
                s1[jt] += v; s2[jt] += v * v;
            }
        }
    }
#pragma unroll
    for (int jt = 0; jt < 4; ++jt) {
        s1[jt] += __shfl_xor(s1[jt], 16); s1[jt] += __shfl_xor(s1[jt], 32);
        s2[jt] += __shfl_xor(s2[jt], 16); s2[jt] += __shfl_xor(s2[jt], 32);
    }
    __syncthreads();
    float* st = (float*)As;   // [8][64]: waves 0..3 sum1, 4..7 sum2
    if (lane < 16) {
#pragma unroll
        for (int jt = 0; jt < 4; ++jt) {
            st[w * 64 + jt * 16 + lane] = s1[jt];
            st[256 + w * 64 + jt * 16 + lane] = s2[jt];
        }
    }
    __syncthreads();
    if (tid < 128) {
        int half = tid >> 6, cl = tid & 63;
        float a = st[half * 64 + cl] + st[(half + 2) * 64 + cl];
        float b = st[256 + half * 64 + cl] + st[256 + (half + 2) * 64 + cl];
        atomicAdd(&s1g[co0 + tid], (double)a);
        atomicAdd(&s2g[co0 + tid], (double)b);
    }
}

// ================= pool: g[b][h] = (1/M) sum_t s[t]*(relu(bn4(y4)) + pe[t][h]) =================
__global__ void k_pool(const unsigned short* __restrict__ y4, const float* __restrict__ sctab,
                       const float* __restrict__ shtab, const float* __restrict__ svec,
                       float* __restrict__ g)
{
    __shared__ float sl[104];
    int b = blockIdx.x;
    int c = blockIdx.y * 256 + threadIdx.x;
    if (threadIdx.x < 104) sl[threadIdx.x] = svec[threadIdx.x];
    __syncthreads();
    float sc = sctab[c], sh = shtab[c];
    int he = c & ~1;
    float div = expf((float)he * (-0.017988946039015984f));   // -ln(10000)/512
    float acc = 0.0f;
    const unsigned short* yb = y4 + (long)b * 104 * 512 + c;
    for (int t = 0; t < 104; ++t) {
        float v = bf2f(yb[t * 512]);
        float hn = fmaxf(fmaf(v, sc, sh), 0.0f);
        float arg = (float)t * div;
        float pe = (c & 1) ? cosf(arg) : sinf(arg);
        acc += sl[t] * (hn + pe);
    }
    g[(long)b * 512 + c] = acc * (1.0f / 104.0f);
}

// ================= 512x512 transpose =================
__global__ void k_t512(const float* __restrict__ in, float* __restrict__ outp)
{
    __shared__ float tile[64 * 68];
    int bx = blockIdx.x, by = blockIdx.y;
    int tid = threadIdx.x;
    for (int it = 0; it < 4; ++it) {
        int s = it * 256 + tid;
        int r = s >> 4, c4 = (s & 15) * 4;
        *(float4*)&tile[r * 68 + c4] = *(const float4*)&in[(long)(bx * 64 + r) * 512 + by * 64 + c4];
    }
    __syncthreads();
    for (int it = 0; it < 4; ++it) {
        int s = it * 256 + tid;
        int r = s >> 4, c4 = (s & 15) * 4;
        float4 v;
        v.x = tile[(c4 + 0) * 68 + r];
        v.y = tile[(c4 + 1) * 68 + r];
        v.z = tile[(c4 + 2) * 68 + r];
        v.w = tile[(c4 + 3) * 68 + r];
        *(float4*)&outp[(long)(by * 64 + r) * 512 + bx * 64 + c4] = v;
    }
}

// fc-stage batch stats
__global__ void k_fcstats(const float* __restrict__ Z, double* __restrict__ s1g, double* __restrict__ s2g)
{
    int strip = blockIdx.x >> 1, half = blockIdx.x & 1;
    int o = half * 256 + threadIdx.x;
    float s1 = 0.f, s2 = 0.f;
    for (int b = strip * 64; b < strip * 64 + 64; ++b) {
        float v = Z[(long)b * 512 + o];
        s1 += v; s2 += v * v;
    }
    atomicAdd(&s1g[o], (double)s1);
    atomicAdd(&s2g[o], (double)s2);
}

// BN(batch) -> exact GELU -> fc2
__global__ __launch_bounds__(256) void k_final(const float* __restrict__ zin, const double* __restrict__ st,
                                               const float* __restrict__ gam, const float* __restrict__ bet,
                                               const float* __restrict__ w2, const float* __restrict__ b2,
                                               float* __restrict__ outp)
{
    __shared__ float red[256];
    int b = blockIdx.x, tid = threadIdx.x;
    int oo[2] = { tid, tid + 256 };
    float gv[2];
#pragma unroll
    for (int q = 0; q < 2; ++q) {
        int o = oo[q];
        double m = st[o] * (1.0 / 512.0);
        double var = st[512 + o] * (1.0 / 512.0) - m * m;
        double rs = 1.0 / sqrt(var + (double)BN_EPS);
        float xn = (float)(((double)zin[(long)b * 512 + o] - m) * rs * (double)gam[o] + (double)bet[o]);
        gv[q] = 0.5f * xn * (1.0f + erff(xn * 0.70710678118654752f));
    }
    for (int n = 0; n < 5; ++n) {
        float p = gv[0] * w2[n * 512 + oo[0]] + gv[1] * w2[n * 512 + oo[1]];
        red[tid] = p;
        __syncthreads();
        for (int off = 128; off; off >>= 1) { if (tid < off) red[tid] += red[tid + off]; __syncthreads(); }
        if (tid == 0) outp[b * 5 + n] = red[0] + b2[n];
        __syncthreads();
    }
}

// ===================== host side =====================
static void mm(hipStream_t s, int Mt, int Nt, int z,
               const float* A, long sA, int lda,
               const float* B, long sB, int ldb,
               float* C, long sC, int ldc,
               int K, int mode, float alpha, float beta,
               const float* aux, long sAux, const float* aux2, int pc, int pr)
{
    dim3 g(Mt, Nt, z);
    k_mm<<<g, 256, 0, s>>>(A, sA, lda, B, sB, ldb, C, sC, ldc, K, mode, alpha, beta, aux, sAux, aux2, pc, pr);
}

extern "C" void kernel_launch(void* const* d_in, const int* in_sizes, int n_in,
                              void* d_out, int out_size, void* d_ws, size_t ws_size,
                              hipStream_t stream)
{
    (void)in_sizes; (void)n_in; (void)out_size;
    const float* x       = (const float*)d_in[0];
    const float* conv_w0 = (const float*)d_in[1];
    const float* conv_b0 = (const float*)d_in[2];
    const float* conv_w  = (const float*)d_in[3];
    const float* conv_b  = (const float*)d_in[4];
    const float* bn_g    = (const float*)d_in[5];
    const float* bn_b    = (const float*)d_in[6];
    const float* proj_w  = (const float*)d_in[7];
    const float* proj_b  = (const float*)d_in[8];
    const float* A_all   = (const float*)d_in[9];
    const float* B_all   = (const float*)d_in[10];
    const float* C_all   = (const float*)d_in[11];
    const float* fc1_w   = (const float*)d_in[12];
    const float* fc1_b   = (const float*)d_in[13];
    const float* fbn_g   = (const float*)d_in[14];
    const float* fbn_b   = (const float*)d_in[15];
    const float* fc2_w   = (const float*)d_in[16];
    const float* fc2_b   = (const float*)d_in[17];
    float* outp = (float*)d_out;
    char* ws = (char*)d_ws;
    if (ws_size < WS_NEED) { printf("ws too small: %zu < %zu\n", ws_size, WS_NEED); return; }

    unsigned short* YBF = (unsigned short*)(ws + OFF_YBF);
    unsigned short* ABF = (unsigned short*)(ws + OFF_ABF);
    unsigned short* WT2 = (unsigned short*)(ws + OFF_WT2);
    unsigned short* ZP  = (unsigned short*)(ws + OFF_ZP);
    float* Xb   = (float*)(ws + OFF_X);
    float* T1   = (float*)(ws + OFF_T1);
    float* T2   = (float*)(ws + OFF_T2);
    float* Eb   = (float*)(ws + OFF_E);
    float* MW   = (float*)(ws + OFF_MW);
    float* ROWT = (float*)(ws + OFF_ROWT);
    float* COLS = (float*)(ws + OFF_COLS);
    float* PIVI = (float*)(ws + OFF_PIVI);
    float* PJT  = (float*)(ws + OFF_PJT);
    float* F1T  = (float*)(ws + OFF_F1T);
    float* G    = (float*)(ws + OFF_G);
    float* POOL = (float*)(ws + OFF_POOL);
    float* Zb   = (float*)(ws + OFF_Z);
    double* ST  = (double*)(ws + OFF_ST);
    float* SC   = (float*)(ws + OFF_SC);
    float* U    = (float*)(ws + OFF_U);
    float* SV   = (float*)(ws + OFF_SV);
    float* V    = (float*)(ws + OFF_V);
    float* WV   = (float*)(ws + OFF_WV);
    float* TRM  = (float*)(ws + OFF_TRM);
    float* SVEC = (float*)(ws + OFF_S);

    const long SM = 262144;   // per-z matrix stride (floats)
    hipMemsetAsync(ws + OFF_ST, 0, 49152, stream);
    hipMemsetAsync(ws + OFF_ZP, 0, 256, stream);

    // ---- conv weights -> bf16 transposed ----
    k_wt2<<<dim3(512, 4), 256, 0, stream>>>(conv_w, WT2);

    // ---- ZOH: expm Taylor (order 4, Horner) ----
    k_build<<<5120, 256, 0, stream>>>(A_all, Xb, MW);
    mm(stream, 8, 8, 5, Xb, SM, 512, Xb, SM, 512, T1, SM, 512, 512, 2, 1.0f/12.0f, 1.0f/3.0f, Xb, SM, nullptr, 0, 0);
    mm(stream, 8, 8, 5, Xb, SM, 512, T1, SM, 512, T2, SM, 512, 512, 2, 0.5f, 0.5f, Xb, SM, nullptr, 0, 0);
    mm(stream, 8, 8, 5, Xb, SM, 512, T2, SM, 512, Eb, SM, 512, 512, 2, 1.0f, 1.0f, Xb, SM, nullptr, 0, 0);
    // A2 = E*E + 2E + I (into Xb), A4 (into T1), A8 (into T2)
    mm(stream, 8, 8, 5, Eb, SM, 512, Eb, SM, 512, Xb, SM, 512, 512, 1, 1.0f, 0.0f, Eb, SM, nullptr, 0, 0);
    mm(stream, 8, 8, 5, Xb, SM, 512, Xb, SM, 512, T1, SM, 512, 512, 0, 1.0f, 0.0f, nullptr, 0, nullptr, 0, 0);
    mm(stream, 8, 8, 5, T1, SM, 512, T1, SM, 512, T2, SM, 512, 512, 0, 1.0f, 0.0f, nullptr, 0, nullptr, 0, 0);
    // ---- blocked Gauss-Jordan sweep inverse of S (MW -> inv(S)) ----
    for (int p = 0; p < 8; ++p) {
        int pc = p * 64;
        k_copycol<<<640, 256, 0, stream>>>(MW, COLS, pc);
        k_inv64<<<5, 256, 0, stream>>>(MW, p, PIVI);
        mm(stream, 1, 8, 5, PIVI, 4096, 64, MW + pc * 512, SM, 512, ROWT, 32768, 512, 64, 3, 1.0f, 0.0f, PIVI, 4096, nullptr, pc, pc);
        mm(stream, 8, 8, 5, COLS, 32768, 64, ROWT, 32768, 512, MW, SM, 512, 64, 4, 1.0f, 0.0f, nullptr, 0, nullptr, pc, pc);
        k_copyrow<<<640, 256, 0, stream>>>(MW, ROWT, pc);
    }
    // ---- B_bar with one fp64-residual refinement step ----
    k_matvecA<<<dim3(512, 5), 64, 0, stream>>>(Eb, SM, B_all, 512, U, 512, nullptr, 0, 0.1f, 0.0f, 0);
    k_matvecA<<<dim3(512, 5), 64, 0, stream>>>(MW, SM, U, 512, V, 4096, nullptr, 0, 1.0f, 0.0f, 0);
    k_matvecA<<<dim3(512, 5), 64, 0, stream>>>(A_all, SM, V, 4096, SV, 512, U, 512, 1.0f, 0.001f, 0);
    k_matvecA<<<dim3(512, 5), 64, 0, stream>>>(MW, SM, SV, 512, V, 4096, nullptr, 0, 1.0f, 0.0f, 1);
    // ---- Krylov: V_{j+1} = (I+E) V_j ; W_{j+1} = W_j * A8 ----
    for (int j = 0; j < 7; ++j)
        k_matvecA<<<dim3(512, 5), 64, 0, stream>>>(Eb, SM, V + j * 512, 4096, V + (j + 1) * 512, 4096, nullptr, 0, 1.0f, 1.0f, 0);
    k_copyW0<<<10, 256, 0, stream>>>(C_all, WV);
    for (int j = 0; j < 12; ++j)
        k_matvecT<<<5, 512, 0, stream>>>(T2, SM, WV + j * 512, 6656, WV + (j + 1) * 512, 6656);
    k_terms<<<5, 256, 0, stream>>>(WV, V, TRM);
    k_skernel<<<1, 128, 0, stream>>>(TRM, SVEC);

    // ---- conv chain (bf16 MFMA) ----
    k_conv0<<<dim3(512, 2), 256, 0, stream>>>(x, conv_w0, conv_b0, YBF, ST, ST + 512);
    k_scaleshift<<<1, 512, 0, stream>>>(ST, bn_g, bn_b, SC, SC + 512, 1.0 / (double)BM);
    for (int l = 1; l <= 4; ++l) {
        k_bnrelu<<<13312, 256, 0, stream>>>(YBF, SC + (l - 1) * 1024, SC + (l - 1) * 1024 + 512, ABF);
        k_convm<<<dim3(416, 4), 256, 0, stream>>>(ABF, WT2 + (size_t)(l - 1) * 3 * 262144,
                                                  conv_b + (l - 1) * 512, ZP, YBF,
                                                  ST + l * 1024, ST + l * 1024 + 512);
        k_scaleshift<<<1, 512, 0, stream>>>(ST + l * 1024, bn_g + l * 512, bn_b + l * 512,
                                            SC + l * 1024, SC + l * 1024 + 512, 1.0 / (double)BM);
    }
    k_pool<<<dim3(512, 2), 256, 0, stream>>>(YBF, SC + 4 * 1024, SC + 4 * 1024 + 512, SVEC, G);

    // ---- head ----
    k_t512<<<dim3(8, 8), 256, 0, stream>>>(proj_w, PJT);
    k_t512<<<dim3(8, 8), 256, 0, stream>>>(fc1_w, F1T);
    mm(stream, 8, 8, 1, G, 0, 512, PJT, 0, 512, POOL, 0, 512, 512, 5, 1.0f, 0.0f, proj_b, 0, SVEC + 104, 0, 0);
    mm(stream, 8, 8, 1, POOL, 0, 512, F1T, 0, 512, Zb, 0, 512, 512, 6, 1.0f, 0.0f, fc1_b, 0, nullptr, 0, 0);
    k_fcstats<<<16, 256, 0, stream>>>(Zb, ST + 5 * 1024, ST + 5 * 1024 + 512);
    k_final<<<512, 256, 0, stream>>>(Zb, ST + 5 * 1024, fbn_g, fbn_b, fc2_w, fc2_b, outp);
}

// Round 3
// 2321.514 us; speedup vs baseline: 2.8983x; 1.0757x over previous
//
#include <hip/hip_runtime.h>
#include <cstdio>
#include <cmath>
#include <cstdint>

// ---------------- problem constants ----------------
constexpr int HH = 512;      // hidden
constexpr int MM_T = 104;    // timesteps
constexpr int BB = 512;      // batch
constexpr int BM = BB * MM_T;       // 53248 rows
constexpr float BN_EPS = 1e-5f;

// ---------------- workspace layout (bytes) ----------------
constexpr size_t SZ_BF   = (size_t)BM * HH * 2;            // 54,525,952
constexpr size_t SZ_MAT5 = (size_t)5 * 512 * 512 * 4;      // 5,242,880
constexpr size_t OFF_YBF = 0;                              // raw conv out, bf16
constexpr size_t OFF_ABF = OFF_YBF + SZ_BF;                // BN+ReLU activations, bf16
constexpr size_t OFF_WT2 = OFF_ABF + SZ_BF;                // conv weights [4][3][co][ci] bf16
constexpr size_t OFF_X   = OFF_WT2 + 6291456;              // X = 0.1*A -> A2 -> P4
constexpr size_t OFF_T1  = OFF_X   + SZ_MAT5;              // temp -> A4
constexpr size_t OFF_T2  = OFF_T1  + SZ_MAT5;              // temp -> A8
constexpr size_t OFF_E   = OFF_T2  + SZ_MAT5;              // E = expm(0.1A) - I -> P2
constexpr size_t OFF_MW  = OFF_E   + SZ_MAT5;              // S -> becomes inv(S)
constexpr size_t OFF_ROWT= OFF_MW  + SZ_MAT5;              // [5][64][512]
constexpr size_t OFF_COLS= OFF_ROWT + 655360;              // [5][512][64] ping
constexpr size_t OFF_COLS2=OFF_COLS + 655360;              // pong
constexpr size_t OFF_PIVI= OFF_COLS2 + 655360;             // [5][64][64]
constexpr size_t OFF_PJT = OFF_PIVI + 81920;               // proj_w^T
constexpr size_t OFF_F1T = OFF_PJT + 1048576;              // fc1_w^T
constexpr size_t OFF_G   = OFF_F1T + 1048576;              // g[b][h]
constexpr size_t OFF_POOL= OFF_G   + 1048576;              // pooled[b][o]
constexpr size_t OFF_Z   = OFF_POOL + 1048576;             // fc1 out
constexpr size_t OFF_ST  = OFF_Z   + 1048576;              // fp64 stats [6][2][512]
constexpr size_t OFF_SC  = OFF_ST  + 49152;                // scale/shift [5][2][512] f32
constexpr size_t OFF_U   = OFF_SC  + 20480;                // u[5][512]
constexpr size_t OFF_SV  = OFF_U   + 10240;                // residual r[5][512]
constexpr size_t OFF_V   = OFF_SV  + 10240;                // V[5][8][512]
constexpr size_t OFF_WV  = OFF_V   + 81920;                // W[5][13][512]
constexpr size_t OFF_TRM = OFF_WV  + 133120;               // terms[5][104]
constexpr size_t OFF_S   = OFF_TRM + 2304;                 // s[104] + sbar
constexpr size_t WS_NEED = OFF_S + 512;

// ---------------- bf16 helpers ----------------
__device__ __forceinline__ float bf2f(unsigned short u) {
    union { uint32_t i; float f; } x; x.i = (uint32_t)u << 16; return x.f;
}
__device__ __forceinline__ unsigned short f2bf(float f) {
    union { float f; uint32_t i; } x; x.f = f;
    uint32_t r = x.i + 0x7FFFu + ((x.i >> 16) & 1u);
    return (unsigned short)(r >> 16);
}

typedef __bf16 bf16x8 __attribute__((ext_vector_type(8)));
typedef float  f32x4  __attribute__((ext_vector_type(4)));

__device__ __forceinline__ void gld16(const void* g, void* l) {
    __builtin_amdgcn_global_load_lds((const __attribute__((address_space(1))) uint32_t*)g,
                                     (__attribute__((address_space(3))) uint32_t*)l, 16, 0, 0);
}

// ================= ZOH: build X = 0.1*A, S = A + 0.001 I, COLS p=0, W0=C =================
__global__ void k_build(const float* __restrict__ Aall, float* __restrict__ X, float* __restrict__ MW,
                        float* __restrict__ COLSa, const float* __restrict__ Call, float* __restrict__ WV)
{
    long i = (long)blockIdx.x * 256 + threadIdx.x;     // 5*262144 total
    float a = Aall[i];
    X[i] = 0.1f * a;
    int z = (int)(i >> 18);
    int rc = (int)(i & 262143);
    int r = rc >> 9, c = rc & 511;
    float mw = a + ((r == c) ? 0.001f : 0.0f);
    MW[i] = mw;
    if (c < 64) COLSa[(long)z * 32768 + r * 64 + c] = mw;
    if (i < 2560) WV[(i >> 9) * 6656 + (i & 511)] = Call[i];
}

// ================= generic batched 64x64-tile fp32 matmul =================
// mode 0: C = alpha*acc
// mode 1: C = acc + 2*aux + I            (A2 = E*E + 2E + I; aux ld = 512)
// mode 2: C = alpha*acc + beta*aux       (expm Horner; aux ld = 512)
// mode 3: GJ row-scale: C = acc, but cols [pc,pc+64) = aux[row][col-pc] (aux=PivInv, ld 64)
// mode 5: C = acc + aux[col]*aux2[0]
// mode 6: C = acc + aux[col]
__global__ __launch_bounds__(256) void k_mm(
    const float* __restrict__ A, long sA, int lda,
    const float* __restrict__ Bm, long sB, int ldb,
    float* __restrict__ C, long sC, int ldc,
    int K, int mode, float alpha, float beta,
    const float* __restrict__ aux, long sAux,
    const float* __restrict__ aux2, int pc, int pr)
{
    __shared__ float sm[2 * 32 * 68];
    float* As = sm;
    float* Bs = sm + 32 * 68;
    int z = blockIdx.z;
    A  += (long)z * sA;
    Bm += (long)z * sB;
    C  += (long)z * sC;
    if (aux) aux += (long)z * sAux;
    int m0 = blockIdx.x * 64, n0 = blockIdx.y * 64;
    int tid = threadIdx.x;
    int tx = tid & 15, ty = tid >> 4;
    float acc[4][4] = {};
    for (int k0 = 0; k0 < K; k0 += 32) {
        __syncthreads();
#pragma unroll
        for (int it = 0; it < 2; ++it) {
            int s = it * 256 + tid;
            int mm = s >> 3, k4 = (s & 7) * 4;
            float4 v = *(const float4*)&A[(long)(m0 + mm) * lda + k0 + k4];
            As[(k4 + 0) * 68 + mm] = v.x;
            As[(k4 + 1) * 68 + mm] = v.y;
            As[(k4 + 2) * 68 + mm] = v.z;
            As[(k4 + 3) * 68 + mm] = v.w;
        }
#pragma unroll
        for (int it = 0; it < 2; ++it) {
            int s = it * 256 + tid;
            int kk = s >> 4, n4 = (s & 15) * 4;
            *(float4*)&Bs[kk * 68 + n4] = *(const float4*)&Bm[(long)(k0 + kk) * ldb + n0 + n4];
        }
        __syncthreads();
#pragma unroll 8
        for (int kk = 0; kk < 32; ++kk) {
            float4 a = *(const float4*)&As[kk * 68 + ty * 4];
            float4 b = *(const float4*)&Bs[kk * 68 + tx * 4];
            float av[4] = {a.x, a.y, a.z, a.w};
            float bv[4] = {b.x, b.y, b.z, b.w};
#pragma unroll
            for (int i = 0; i < 4; ++i)
#pragma unroll
                for (int j = 0; j < 4; ++j)
                    acc[i][j] = fmaf(av[i], bv[j], acc[i][j]);
        }
    }
    float sc2 = (mode == 5) ? aux2[0] : 0.0f;
#pragma unroll
    for (int i = 0; i < 4; ++i) {
        int row = m0 + ty * 4 + i;
        int col0 = n0 + tx * 4;
        long base = (long)row * ldc + col0;
        float v[4];
#pragma unroll
        for (int j = 0; j < 4; ++j) v[j] = acc[i][j];
        if (mode == 0) {
            for (int j = 0; j < 4; ++j) v[j] *= alpha;
        } else if (mode == 1) {
            for (int j = 0; j < 4; ++j) {
                int col = col0 + j;
                v[j] = v[j] + 2.0f * aux[(long)row * 512 + col] + ((row == col) ? 1.0f : 0.0f);
            }
        } else if (mode == 2) {
            for (int j = 0; j < 4; ++j)
                v[j] = alpha * v[j] + beta * aux[(long)row * 512 + col0 + j];
        } else if (mode == 3) {
            bool inP = (col0 >= pc && col0 < pc + 64);
            if (inP)
                for (int j = 0; j < 4; ++j) v[j] = aux[row * 64 + (col0 + j - pc)];
        } else if (mode == 5) {
            for (int j = 0; j < 4; ++j) v[j] += aux[col0 + j] * sc2;
        } else if (mode == 6) {
            for (int j = 0; j < 4; ++j) v[j] += aux[col0 + j];
        }
        *(float4*)&C[base] = make_float4(v[0], v[1], v[2], v[3]);
    }
}

// ================= fused GJ elimination step =================
// For m0 != pr:  MW_tile = (n0==pr ? 0 : MW_old) - COLSc[m rows] x ROWT[:, n cols]
// For m0 == pr:  MW_tile = ROWT tile (pivot-row copy)
// Any tile with n0 == pcn also emits its new values into COLSn (next iteration's A).
__global__ __launch_bounds__(256) void k_elim(
    const float* __restrict__ COLSc, const float* __restrict__ ROWT,
    float* __restrict__ MW, float* __restrict__ COLSn, int pr, int pcn)
{
    int z = blockIdx.z;
    COLSc += (long)z * 32768; ROWT += (long)z * 32768;
    MW += (long)z * 262144; COLSn += (long)z * 32768;
    int m0 = blockIdx.x * 64, n0 = blockIdx.y * 64;
    int tid = threadIdx.x;
    if (m0 == pr) {
        for (int it = 0; it < 16; ++it) {
            int idx = it * 256 + tid;
            int r = idx >> 6, c = idx & 63;
            float v = ROWT[r * 512 + n0 + c];
            MW[(long)(pr + r) * 512 + n0 + c] = v;
            if (n0 == pcn) COLSn[(pr + r) * 64 + c] = v;
        }
        return;
    }
    __shared__ float As[64 * 68];
    __shared__ float Bs[64 * 68];
    {
        int m = tid >> 2, kb = (tid & 3) * 16;
#pragma unroll
        for (int u = 0; u < 4; ++u) {
            float4 v = *(const float4*)&COLSc[(m0 + m) * 64 + kb + u * 4];
            As[(kb + u * 4 + 0) * 68 + m] = v.x;
            As[(kb + u * 4 + 1) * 68 + m] = v.y;
            As[(kb + u * 4 + 2) * 68 + m] = v.z;
            As[(kb + u * 4 + 3) * 68 + m] = v.w;
        }
        int kr = tid >> 2, nb = (tid & 3) * 16;
#pragma unroll
        for (int u = 0; u < 4; ++u)
            *(float4*)&Bs[kr * 68 + nb + u * 4] = *(const float4*)&ROWT[kr * 512 + n0 + nb + u * 4];
    }
    __syncthreads();
    int tx = tid & 15, ty = tid >> 4;
    float acc[4][4] = {};
#pragma unroll 8
    for (int kk = 0; kk < 64; ++kk) {
        float4 a = *(const float4*)&As[kk * 68 + ty * 4];
        float4 b = *(const float4*)&Bs[kk * 68 + tx * 4];
        float av[4] = {a.x, a.y, a.z, a.w};
        float bv[4] = {b.x, b.y, b.z, b.w};
#pragma unroll
        for (int i = 0; i < 4; ++i)
#pragma unroll
            for (int j = 0; j < 4; ++j)
                acc[i][j] = fmaf(av[i], bv[j], acc[i][j]);
    }
    bool inP = (n0 == pr);
#pragma unroll
    for (int i = 0; i < 4; ++i) {
        int row = m0 + ty * 4 + i;
        int col0 = n0 + tx * 4;
        long base = (long)row * 512 + col0;
        float ov[4] = {0.f, 0.f, 0.f, 0.f};
        if (!inP) {
            float4 oldv = *(const float4*)&MW[base];
            ov[0] = oldv.x; ov[1] = oldv.y; ov[2] = oldv.z; ov[3] = oldv.w;
        }
        float v[4];
#pragma unroll
        for (int j = 0; j < 4; ++j) v[j] = ov[j] - acc[i][j];
        *(float4*)&MW[base] = make_float4(v[0], v[1], v[2], v[3]);
        if (n0 == pcn)
            *(float4*)&COLSn[row * 64 + (col0 - pcn)] = make_float4(v[0], v[1], v[2], v[3]);
    }
}

// ================= pivoted 64x64 Gauss-Jordan inverse in LDS =================
__global__ __launch_bounds__(256) void k_inv64(float* __restrict__ MW, int pblk, float* __restrict__ PIVI)
{
    __shared__ float mat[64][65];
    __shared__ int perm[64];
    __shared__ int pividx;
    int z = blockIdx.x;
    float* Mg = MW + (long)z * 262144 + (long)pblk * 64 * 512 + pblk * 64;
    int tid = threadIdx.x;
    for (int it = 0; it < 16; ++it) {
        int idx = it * 256 + tid;
        int r = idx >> 6, c = idx & 63;
        mat[r][c] = Mg[r * 512 + c];
    }
    __syncthreads();
    for (int j = 0; j < 64; ++j) {
        if (tid == 0) {
            int best = j; float bv = fabsf(mat[j][j]);
            for (int i = j + 1; i < 64; ++i) {
                float a = fabsf(mat[i][j]);
                if (a > bv) { bv = a; best = i; }
            }
            perm[j] = best; pividx = best;
        }
        __syncthreads();
        int r = pividx;
        if (r != j && tid < 64) {
            float t = mat[j][tid]; mat[j][tid] = mat[r][tid]; mat[r][tid] = t;
        }
        __syncthreads();
        float pv = mat[j][j];
        __syncthreads();
        float d = 1.0f / pv;
        if (tid < 64) mat[j][tid] = (tid == j) ? d : mat[j][tid] * d;
        __syncthreads();
        __shared__ float fv[64];
        if (tid < 64) fv[tid] = mat[tid][j];
        __syncthreads();
        {
            int i = tid & 63, cc = tid >> 6;
            if (i != j) {
                float f = fv[i];
#pragma unroll
                for (int c0 = 0; c0 < 16; ++c0) {
                    int c = cc * 16 + c0;
                    float val = mat[i][c] - f * mat[j][c];
                    if (c == j) val = -f * d;
                    mat[i][c] = val;
                }
            }
        }
        __syncthreads();
    }
    for (int j = 63; j >= 0; --j) {
        int r = perm[j];
        if (r != j && tid < 64) {
            float t = mat[tid][j]; mat[tid][j] = mat[tid][r]; mat[tid][r] = t;
        }
        __syncthreads();
    }
    float* Pg = PIVI + z * 4096;
    for (int it = 0; it < 16; ++it) {
        int idx = it * 256 + tid;
        int r = idx >> 6, c = idx & 63;
        Pg[r * 64 + c] = mat[r][c];
    }
}

// ================= batched matvec: y = alpha*(A x) + beta*x  (B_bar path) =================
__global__ void k_matvecA(const float* __restrict__ A, long sA,
                          const float* __restrict__ x, long sx,
                          float* __restrict__ y, long sy,
                          const float* __restrict__ sub, long ssub,
                          float alpha, float beta, int accum)
{
    int row = blockIdx.x, z = blockIdx.y, lane = threadIdx.x;
    A += (long)z * sA; x += (long)z * sx; y += (long)z * sy;
    if (sub) sub += (long)z * ssub;
    const float* ar = A + (long)row * 512;
    double acc = 0.0;
#pragma unroll
    for (int m = 0; m < 8; ++m) {
        int k = lane + m * 64;
        acc += (double)ar[k] * (double)x[k];
    }
    for (int off = 32; off; off >>= 1) acc += __shfl_down(acc, off);
    if (lane == 0) {
        float val = alpha * (float)acc + beta * x[row];
        if (sub) val = sub[row] - val;
        if (accum) y[row] += val; else y[row] = val;
    }
}

// multi-row batched matvec for the V chain: y_r = alpha*(A x_r) + beta*x_r
__global__ void k_matvecB(const float* __restrict__ A,
                          const float* __restrict__ xb, float* __restrict__ yb,
                          int sxr, int syr, float alpha, float beta)
{
    int row = blockIdx.x, z = blockIdx.y, r = blockIdx.z, lane = threadIdx.x;
    const float* x = xb + (long)z * 4096 + r * sxr;
    float* y = yb + (long)z * 4096 + r * syr;
    const float* ar = A + (long)z * 262144 + (long)row * 512;
    double acc = 0.0;
#pragma unroll
    for (int m = 0; m < 8; ++m) {
        int k = lane + m * 64;
        acc += (double)ar[k] * (double)x[k];
    }
    for (int off = 32; off; off >>= 1) acc += __shfl_down(acc, off);
    if (lane == 0) y[row] = alpha * (float)acc + beta * x[row];
}

// multi-row W chain: W[dst0+r] = W[src0+r]^T * Amat
__global__ __launch_bounds__(512) void k_matvecTm(const float* __restrict__ A,
                                                  float* __restrict__ WVb, int src0, int dst0)
{
    __shared__ float wl[512];
    int z = blockIdx.x, r = blockIdx.y, tid = threadIdx.x;
    A += (long)z * 262144;
    wl[tid] = WVb[z * 6656 + (src0 + r) * 512 + tid];
    __syncthreads();
    double acc = 0.0;
#pragma unroll 8
    for (int j = 0; j < 512; ++j)
        acc += (double)A[(long)j * 512 + tid] * (double)wl[j];
    WVb[z * 6656 + (dst0 + r) * 512 + tid] = (float)acc;
}

// terms[z][8j+i] = W[z][j] . V[z][i]
__global__ void k_terms(const float* __restrict__ WV, const float* __restrict__ V, float* __restrict__ terms)
{
    int z = blockIdx.x, tid = threadIdx.x;
    int lane = tid & 63, wv = tid >> 6;
    for (int d = wv; d < 104; d += 4) {
        int j = d >> 3, i = d & 7;
        const float* wp = WV + z * 6656 + j * 512;
        const float* vp = V + z * 4096 + i * 512;
        float acc = 0.0f;
#pragma unroll
        for (int m = 0; m < 8; ++m) {
            int k = lane + m * 64;
            acc += wp[k] * vp[k];
        }
        for (int off = 32; off; off >>= 1) acc += __shfl_down(acc, off);
        if (lane == 0) terms[z * 104 + d] = acc;
    }
}

// s[t] = prod_l flip(terms_l)[t]/(||terms_l||+1e-6);  s[104] = mean_t s[t]
__global__ __launch_bounds__(128) void k_skernel(const float* __restrict__ terms, float* __restrict__ svec)
{
    __shared__ float red[128];
    __shared__ float invn[5];
    int tid = threadIdx.x;
    for (int l = 0; l < 5; ++l) {
        float v = (tid < 104) ? terms[l * 104 + tid] : 0.0f;
        red[tid] = v * v;
        __syncthreads();
        for (int off = 64; off; off >>= 1) { if (tid < off) red[tid] += red[tid + off]; __syncthreads(); }
        if (tid == 0) invn[l] = 1.0f / (sqrtf(red[0]) + 1e-6f);
        __syncthreads();
    }
    float s = 0.0f;
    if (tid < 104) {
        s = 1.0f;
        for (int l = 0; l < 5; ++l) s *= terms[l * 104 + (103 - tid)] * invn[l];
        svec[tid] = s;
    }
    red[tid] = (tid < 104) ? s : 0.0f;
    __syncthreads();
    for (int off = 64; off; off >>= 1) { if (tid < off) red[tid] += red[tid + off]; __syncthreads(); }
    if (tid == 0) svec[104] = red[0] * (1.0f / 104.0f);
}

// ================= conv0 (1->H) + stats, bf16 out =================
__global__ void k_conv0(const float* __restrict__ x, const float* __restrict__ w0, const float* __restrict__ b0,
                        unsigned short* __restrict__ y, double* __restrict__ s1g, double* __restrict__ s2g)
{
    int b = blockIdx.x;
    int c = blockIdx.y * 256 + threadIdx.x;
    float w_0 = w0[c * 3 + 0], w_1 = w0[c * 3 + 1], w_2 = w0[c * 3 + 2], bb = b0[c];
    const float* xb = x + b * 104;
    unsigned short* yb = y + (long)b * 104 * 512 + c;
    float xm2 = 0.0f, xm1 = 0.0f;
    float s1 = 0.0f, s2 = 0.0f;
    for (int t = 0; t < 104; ++t) {
        float x0 = xb[t];
        float v = w_0 * xm2 + w_1 * xm1 + w_2 * x0 + bb;
        yb[t * 512] = f2bf(v);
        s1 += v; s2 += v * v;
        xm2 = xm1; xm1 = x0;
    }
    atomicAdd(&s1g[c], (double)s1);
    atomicAdd(&s2g[c], (double)s2);
}

// per-channel scale/shift from fp64 stats
__global__ void k_scaleshift(const double* __restrict__ st, const float* __restrict__ gam,
                             const float* __restrict__ bet, float* __restrict__ sc, float* __restrict__ sh,
                             double invN)
{
    int c = threadIdx.x;
    double m = st[c] * invN;
    double v = st[512 + c] * invN - m * m;
    double rs = 1.0 / sqrt(v + (double)BN_EPS);
    double scale = (double)gam[c] * rs;
    sc[c] = (float)scale;
    sh[c] = (float)((double)bet[c] - m * scale);
}

// conv weights -> bf16 [l][tap][co][ci]
__global__ void k_wt2(const float* __restrict__ W, unsigned short* __restrict__ Wt2)
{
    int co = blockIdx.x, l = blockIdx.y, tid = threadIdx.x;
    const float* src = W + (long)(l * 512 + co) * 512 * 3;
    unsigned short* dst = Wt2 + (long)l * 3 * 262144 + ((long)co << 9);
#pragma unroll
    for (int q = 0; q < 2; ++q) {
        int ci = tid * 2 + q;
        float f0 = src[ci * 3 + 0], f1 = src[ci * 3 + 1], f2 = src[ci * 3 + 2];
        dst[ci] = f2bf(f0);
        dst[262144 + ci] = f2bf(f1);
        dst[524288 + ci] = f2bf(f2);
    }
}

// BN+ReLU elementwise: act = max(sc*y+sh, 0), bf16 in/out
__global__ __launch_bounds__(256) void k_bnrelu(const unsigned short* __restrict__ y,
                                                const float* __restrict__ sc, const float* __restrict__ sh,
                                                unsigned short* __restrict__ a)
{
    long idx = (long)blockIdx.x * 256 + threadIdx.x;
    long e = idx * 8;
    int c0 = (int)(e & 511);
    uint4 v = *(const uint4*)(y + e);
    float4 s0 = *(const float4*)(sc + c0);
    float4 s1 = *(const float4*)(sc + c0 + 4);
    float4 h0 = *(const float4*)(sh + c0);
    float4 h1 = *(const float4*)(sh + c0 + 4);
    unsigned short u[8];
    u[0] = (unsigned short)(v.x & 0xFFFF); u[1] = (unsigned short)(v.x >> 16);
    u[2] = (unsigned short)(v.y & 0xFFFF); u[3] = (unsigned short)(v.y >> 16);
    u[4] = (unsigned short)(v.z & 0xFFFF); u[5] = (unsigned short)(v.z >> 16);
    u[6] = (unsigned short)(v.w & 0xFFFF); u[7] = (unsigned short)(v.w >> 16);
    float ss[8] = {s0.x, s0.y, s0.z, s0.w, s1.x, s1.y, s1.z, s1.w};
    float hh[8] = {h0.x, h0.y, h0.z, h0.w, h1.x, h1.y, h1.z, h1.w};
    unsigned short o[8];
#pragma unroll
    for (int j = 0; j < 8; ++j) {
        float f = fmaxf(fmaf(bf2f(u[j]), ss[j], hh[j]), 0.0f);
        o[j] = f2bf(f);
    }
    uint4 w;
    w.x = (uint32_t)o[0] | ((uint32_t)o[1] << 16);
    w.y = (uint32_t)o[2] | ((uint32_t)o[3] << 16);
    w.z = (uint32_t)o[4] | ((uint32_t)o[5] << 16);
    w.w = (uint32_t)o[6] | ((uint32_t)o[7] << 16);
    *(uint4*)(a + e) = w;
}

// ================= MFMA conv GEMM, tap-fused single A-stage =================
// A rows m0-2..m0+127 staged once per K-slice; 3 taps read with row offset + causal mask.
__global__ __launch_bounds__(256) void k_convm(
    const unsigned short* __restrict__ act,
    const unsigned short* __restrict__ Wt2,      // layer base [3][512][512]
    const float* __restrict__ bias,
    unsigned short* __restrict__ yout,
    double* __restrict__ s1g, double* __restrict__ s2g)
{
    __shared__ __align__(16) unsigned short As[130 * 32];     // 8320 elems
    __shared__ __align__(16) unsigned short Bs[3 * 128 * 32]; // 12288 elems
    int tid = threadIdx.x;
    int m0 = blockIdx.x * 128, co0 = blockIdx.y * 128;
    int w = tid >> 6, lane = tid & 63;
    int wr = (w >> 1) * 64, wc = (w & 1) * 64;
    int fr = lane & 15, fkb = (lane >> 4) * 8, quad = lane >> 4;

    // causal validity: for output row R (time t), tap tau contributes iff t+tau>=2
    bool valid[4][3];
#pragma unroll
    for (int i = 0; i < 4; ++i) {
        int R = m0 + wr + i * 16 + fr;
        int t = R % 104;
#pragma unroll
        for (int tau = 0; tau < 3; ++tau) valid[i][tau] = (t + tau >= 2);
    }
    // A staging: chunks q=tid, 256+tid, 512+tid(tid<8); row=q>>2 (LDS row = global m0-2+row), k=(q&3)*8
    int ka = (tid & 3) * 8;
    int g0 = m0 - 2 + (tid >> 2); if (g0 < 0) g0 = 0;
    int g1 = m0 + 62 + (tid >> 2);
    int g2 = m0 + 126 + (tid >> 2);           // only tid<8 uses (rows 128,129)
    const unsigned short* pa0 = act + (long)g0 * 512 + ka;
    const unsigned short* pa1 = act + (long)g1 * 512 + ka;
    const unsigned short* pa2 = act + (long)g2 * 512 + ka;
    // B staging: 6 chunks/thread: c=it*256+tid -> tau=c>>9, row=(c>>2)&127, k=(c&3)*8
    const unsigned short* pb[6];
#pragma unroll
    for (int it = 0; it < 6; ++it) {
        int c = it * 256 + tid;
        int tau = c >> 9, r = (c >> 2) & 127, kq = (c & 3) * 8;
        pb[it] = Wt2 + ((long)tau << 18) + ((long)(co0 + r) << 9) + kq;
    }

    f32x4 zero4 = {0.f, 0.f, 0.f, 0.f};
    f32x4 acc[4][4];
#pragma unroll
    for (int i = 0; i < 4; ++i)
#pragma unroll
        for (int j = 0; j < 4; ++j) acc[i][j] = zero4;
    bf16x8 zer = {0, 0, 0, 0, 0, 0, 0, 0};

#pragma unroll 1
    for (int s = 0; s < 16; ++s) {
        int ci0 = s * 32;
        __syncthreads();
        gld16(pa0 + ci0, &As[tid * 8]);
        gld16(pa1 + ci0, &As[2048 + tid * 8]);
        if (tid < 8) gld16(pa2 + ci0, &As[4096 + tid * 8]);
#pragma unroll
        for (int it = 0; it < 6; ++it)
            gld16(pb[it] + ci0, &Bs[it * 2048 + tid * 8]);
        __syncthreads();
#pragma unroll
        for (int tau = 0; tau < 3; ++tau) {
            bf16x8 af[4], bfr[4];
#pragma unroll
            for (int i = 0; i < 4; ++i) {
                bf16x8 raw = *(const bf16x8*)&As[(wr + i * 16 + fr + tau) * 32 + fkb];
                af[i] = valid[i][tau] ? raw : zer;
            }
#pragma unroll
            for (int j = 0; j < 4; ++j)
                bfr[j] = *(const bf16x8*)&Bs[tau * 4096 + (wc + j * 16 + fr) * 32 + fkb];
#pragma unroll
            for (int i = 0; i < 4; ++i)
#pragma unroll
                for (int j = 0; j < 4; ++j)
                    acc[i][j] = __builtin_amdgcn_mfma_f32_16x16x32_bf16(af[i], bfr[j], acc[i][j], 0, 0, 0);
        }
    }
    // epilogue: bias, bf16 store, per-channel stats
    float bcol[4], s1[4] = {0, 0, 0, 0}, s2[4] = {0, 0, 0, 0};
#pragma unroll
    for (int jt = 0; jt < 4; ++jt) bcol[jt] = bias[co0 + wc + jt * 16 + fr];
#pragma unroll
    for (int i = 0; i < 4; ++i) {
        int rbase = m0 + wr + i * 16 + quad * 4;
#pragma unroll
        for (int jt = 0; jt < 4; ++jt) {
            int col = co0 + wc + jt * 16 + fr;
#pragma unroll
            for (int r = 0; r < 4; ++r) {
                float v = acc[i][jt][r] + bcol[jt];
                yout[(long)(rbase + r) * 512 + col] = f2bf(v);
                s1[jt] += v; s2[jt] += v * v;
            }
        }
    }
#pragma unroll
    for (int jt = 0; jt < 4; ++jt) {
        s1[jt] += __shfl_xor(s1[jt], 16); s1[jt] += __shfl_xor(s1[jt], 32);
        s2[jt] += __shfl_xor(s2[jt], 16); s2[jt] += __shfl_xor(s2[jt], 32);
    }
    __syncthreads();
    float* st = (float*)As;   // [8][64]: waves 0..3 sum1, 4..7 sum2
    if (lane < 16) {
#pragma unroll
        for (int jt = 0; jt < 4; ++jt) {
            st[w * 64 + jt * 16 + lane] = s1[jt];
            st[256 + w * 64 + jt * 16 + lane] = s2[jt];
        }
    }
    __syncthreads();
    if (tid < 128) {
        int half = tid >> 6, cl = tid & 63;
        float a = st[half * 64 + cl] + st[(half + 2) * 64 + cl];
        float b = st[256 + half * 64 + cl] + st[256 + (half + 2) * 64 + cl];
        atomicAdd(&s1g[co0 + tid], (double)a);
        atomicAdd(&s2g[co0 + tid], (double)b);
    }
}

// ================= pool: g[b][h] = (1/M) sum_t s[t]*(relu(bn4(y4)) + pe[t][h]) =================
__global__ void k_pool(const unsigned short* __restrict__ y4, const float* __restrict__ sctab,
                       const float* __restrict__ shtab, const float* __restrict__ svec,
                       float* __restrict__ g)
{
    __shared__ float sl[104];
    int b = blockIdx.x;
    int c = blockIdx.y * 256 + threadIdx.x;
    if (threadIdx.x < 104) sl[threadIdx.x] = svec[threadIdx.x];
    __syncthreads();
    float sc = sctab[c], sh = shtab[c];
    int he = c & ~1;
    float div = expf((float)he * (-0.017988946039015984f));   // -ln(10000)/512
    float acc = 0.0f;
    const unsigned short* yb = y4 + (long)b * 104 * 512 + c;
    for (int t = 0; t < 104; ++t) {
        float v = bf2f(yb[t * 512]);
        float hn = fmaxf(fmaf(v, sc, sh), 0.0f);
        float arg = (float)t * div;
        float pe = (c & 1) ? cosf(arg) : sinf(arg);
        acc += sl[t] * (hn + pe);
    }
    g[(long)b * 512 + c] = acc * (1.0f / 104.0f);
}

// ================= dual 512x512 transpose =================
__global__ void k_t512(const float* __restrict__ in0, float* __restrict__ out0,
                       const float* __restrict__ in1, float* __restrict__ out1)
{
    __shared__ float tile[64 * 68];
    const float* in = blockIdx.z ? in1 : in0;
    float* outp = blockIdx.z ? out1 : out0;
    int bx = blockIdx.x, by = blockIdx.y;
    int tid = threadIdx.x;
    for (int it = 0; it < 4; ++it) {
        int s = it * 256 + tid;
        int r = s >> 4, c4 = (s & 15) * 4;
        *(float4*)&tile[r * 68 + c4] = *(const float4*)&in[(long)(bx * 64 + r) * 512 + by * 64 + c4];
    }
    __syncthreads();
    for (int it = 0; it < 4; ++it) {
        int s = it * 256 + tid;
        int r = s >> 4, c4 = (s & 15) * 4;
        float4 v;
        v.x = tile[(c4 + 0) * 68 + r];
        v.y = tile[(c4 + 1) * 68 + r];
        v.z = tile[(c4 + 2) * 68 + r];
        v.w = tile[(c4 + 3) * 68 + r];
        *(float4*)&outp[(long)(by * 64 + r) * 512 + bx * 64 + c4] = v;
    }
}

// fc-stage batch stats
__global__ void k_fcstats(const float* __restrict__ Z, double* __restrict__ s1g, double* __restrict__ s2g)
{
    int strip = blockIdx.x >> 1, half = blockIdx.x & 1;
    int o = half * 256 + threadIdx.x;
    float s1 = 0.f, s2 = 0.f;
    for (int b = strip * 64; b < strip * 64 + 64; ++b) {
        float v = Z[(long)b * 512 + o];
        s1 += v; s2 += v * v;
    }
    atomicAdd(&s1g[o], (double)s1);
    atomicAdd(&s2g[o], (double)s2);
}

// BN(batch) -> exact GELU -> fc2
__global__ __launch_bounds__(256) void k_final(const float* __restrict__ zin, const double* __restrict__ st,
                                               const float* __restrict__ gam, const float* __restrict__ bet,
                                               const float* __restrict__ w2, const float* __restrict__ b2,
                                               float* __restrict__ outp)
{
    __shared__ float red[256];
    int b = blockIdx.x, tid = threadIdx.x;
    int oo[2] = { tid, tid + 256 };
    float gv[2];
#pragma unroll
    for (int q = 0; q < 2; ++q) {
        int o = oo[q];
        double m = st[o] * (1.0 / 512.0);
        double var = st[512 + o] * (1.0 / 512.0) - m * m;
        double rs = 1.0 / sqrt(var + (double)BN_EPS);
        float xn = (float)(((double)zin[(long)b * 512 + o] - m) * rs * (double)gam[o] + (double)bet[o]);
        gv[q] = 0.5f * xn * (1.0f + erff(xn * 0.70710678118654752f));
    }
    for (int n = 0; n < 5; ++n) {
        float p = gv[0] * w2[n * 512 + oo[0]] + gv[1] * w2[n * 512 + oo[1]];
        red[tid] = p;
        __syncthreads();
        for (int off = 128; off; off >>= 1) { if (tid < off) red[tid] += red[tid + off]; __syncthreads(); }
        if (tid == 0) outp[b * 5 + n] = red[0] + b2[n];
        __syncthreads();
    }
}

// ===================== host side =====================
static void mm(hipStream_t s, int Mt, int Nt, int z,
               const float* A, long sA, int lda,
               const float* B, long sB, int ldb,
               float* C, long sC, int ldc,
               int K, int mode, float alpha, float beta,
               const float* aux, long sAux, const float* aux2, int pc, int pr)
{
    dim3 g(Mt, Nt, z);
    k_mm<<<g, 256, 0, s>>>(A, sA, lda, B, sB, ldb, C, sC, ldc, K, mode, alpha, beta, aux, sAux, aux2, pc, pr);
}

extern "C" void kernel_launch(void* const* d_in, const int* in_sizes, int n_in,
                              void* d_out, int out_size, void* d_ws, size_t ws_size,
                              hipStream_t stream)
{
    (void)in_sizes; (void)n_in; (void)out_size;
    const float* x       = (const float*)d_in[0];
    const float* conv_w0 = (const float*)d_in[1];
    const float* conv_b0 = (const float*)d_in[2];
    const float* conv_w  = (const float*)d_in[3];
    const float* conv_b  = (const float*)d_in[4];
    const float* bn_g    = (const float*)d_in[5];
    const float* bn_b    = (const float*)d_in[6];
    const float* proj_w  = (const float*)d_in[7];
    const float* proj_b  = (const float*)d_in[8];
    const float* A_all   = (const float*)d_in[9];
    const float* B_all   = (const float*)d_in[10];
    const float* C_all   = (const float*)d_in[11];
    const float* fc1_w   = (const float*)d_in[12];
    const float* fc1_b   = (const float*)d_in[13];
    const float* fbn_g   = (const float*)d_in[14];
    const float* fbn_b   = (const float*)d_in[15];
    const float* fc2_w   = (const float*)d_in[16];
    const float* fc2_b   = (const float*)d_in[17];
    float* outp = (float*)d_out;
    char* ws = (char*)d_ws;
    if (ws_size < WS_NEED) { printf("ws too small: %zu < %zu\n", ws_size, WS_NEED); return; }

    unsigned short* YBF = (unsigned short*)(ws + OFF_YBF);
    unsigned short* ABF = (unsigned short*)(ws + OFF_ABF);
    unsigned short* WT2 = (unsigned short*)(ws + OFF_WT2);
    float* Xb   = (float*)(ws + OFF_X);
    float* T1   = (float*)(ws + OFF_T1);
    float* T2   = (float*)(ws + OFF_T2);
    float* Eb   = (float*)(ws + OFF_E);
    float* MW   = (float*)(ws + OFF_MW);
    float* ROWT = (float*)(ws + OFF_ROWT);
    float* COLS1= (float*)(ws + OFF_COLS);
    float* COLS2= (float*)(ws + OFF_COLS2);
    float* PIVI = (float*)(ws + OFF_PIVI);
    float* PJT  = (float*)(ws + OFF_PJT);
    float* F1T  = (float*)(ws + OFF_F1T);
    float* G    = (float*)(ws + OFF_G);
    float* POOL = (float*)(ws + OFF_POOL);
    float* Zb   = (float*)(ws + OFF_Z);
    double* ST  = (double*)(ws + OFF_ST);
    float* SC   = (float*)(ws + OFF_SC);
    float* U    = (float*)(ws + OFF_U);
    float* SV   = (float*)(ws + OFF_SV);
    float* V    = (float*)(ws + OFF_V);
    float* WV   = (float*)(ws + OFF_WV);
    float* TRM  = (float*)(ws + OFF_TRM);
    float* SVEC = (float*)(ws + OFF_S);

    const long SM = 262144;   // per-z matrix stride (floats)
    hipMemsetAsync(ws + OFF_ST, 0, 49152, stream);

    // ---- conv weights -> bf16 ----
    k_wt2<<<dim3(512, 4), 256, 0, stream>>>(conv_w, WT2);

    // ---- ZOH: expm Taylor (order 4, Horner) ----
    k_build<<<5120, 256, 0, stream>>>(A_all, Xb, MW, COLS1, C_all, WV);
    mm(stream, 8, 8, 5, Xb, SM, 512, Xb, SM, 512, T1, SM, 512, 512, 2, 1.0f/12.0f, 1.0f/3.0f, Xb, SM, nullptr, 0, 0);
    mm(stream, 8, 8, 5, Xb, SM, 512, T1, SM, 512, T2, SM, 512, 512, 2, 0.5f, 0.5f, Xb, SM, nullptr, 0, 0);
    mm(stream, 8, 8, 5, Xb, SM, 512, T2, SM, 512, Eb, SM, 512, 512, 2, 1.0f, 1.0f, Xb, SM, nullptr, 0, 0);
    // A2 = E*E + 2E + I (into Xb), A4 (into T1), A8 (into T2)
    mm(stream, 8, 8, 5, Eb, SM, 512, Eb, SM, 512, Xb, SM, 512, 512, 1, 1.0f, 0.0f, Eb, SM, nullptr, 0, 0);
    mm(stream, 8, 8, 5, Xb, SM, 512, Xb, SM, 512, T1, SM, 512, 512, 0, 1.0f, 0.0f, nullptr, 0, nullptr, 0, 0);
    mm(stream, 8, 8, 5, T1, SM, 512, T1, SM, 512, T2, SM, 512, 512, 0, 1.0f, 0.0f, nullptr, 0, nullptr, 0, 0);
    // ---- blocked Gauss-Jordan sweep inverse of S (MW -> inv(S)), fused copies ----
    for (int p = 0; p < 8; ++p) {
        int pc = p * 64;
        float* Cc = (p & 1) ? COLS2 : COLS1;
        float* Cn = (p & 1) ? COLS1 : COLS2;
        k_inv64<<<5, 256, 0, stream>>>(MW, p, PIVI);
        mm(stream, 1, 8, 5, PIVI, 4096, 64, MW + pc * 512, SM, 512, ROWT, 32768, 512, 64, 3, 1.0f, 0.0f, PIVI, 4096, nullptr, pc, pc);
        k_elim<<<dim3(8, 8, 5), 256, 0, stream>>>(Cc, ROWT, MW, Cn, pc, pc + 64);
    }
    // ---- B_bar with one fp64-residual refinement step ----
    k_matvecA<<<dim3(512, 5), 64, 0, stream>>>(Eb, SM, B_all, 512, U, 512, nullptr, 0, 0.1f, 0.0f, 0);
    k_matvecA<<<dim3(512, 5), 64, 0, stream>>>(MW, SM, U, 512, V, 4096, nullptr, 0, 1.0f, 0.0f, 0);
    k_matvecA<<<dim3(512, 5), 64, 0, stream>>>(A_all, SM, V, 4096, SV, 512, U, 512, 1.0f, 0.001f, 0);
    k_matvecA<<<dim3(512, 5), 64, 0, stream>>>(MW, SM, SV, 512, V, 4096, nullptr, 0, 1.0f, 0.0f, 1);
    // ---- V chain via binary powers: V1 = Abar V0; V{2,3} = A2 V{0,1}; V{4..7} = A4 V{0..3} ----
    k_matvecB<<<dim3(512, 5, 1), 64, 0, stream>>>(Eb, V, V + 512, 512, 512, 1.0f, 1.0f);
    k_matvecB<<<dim3(512, 5, 2), 64, 0, stream>>>(Xb, V, V + 1024, 512, 512, 1.0f, 0.0f);
    k_matvecB<<<dim3(512, 5, 4), 64, 0, stream>>>(T1, V, V + 2048, 512, 512, 1.0f, 0.0f);
    // ---- W chain: P2 = A8^2 (into Eb), P4 = P2^2 (into Xb) ----
    mm(stream, 8, 8, 5, T2, SM, 512, T2, SM, 512, Eb, SM, 512, 512, 0, 1.0f, 0.0f, nullptr, 0, nullptr, 0, 0);
    mm(stream, 8, 8, 5, Eb, SM, 512, Eb, SM, 512, Xb, SM, 512, 512, 0, 1.0f, 0.0f, nullptr, 0, nullptr, 0, 0);
    k_matvecTm<<<dim3(5, 1), 512, 0, stream>>>(T2, WV, 0, 1);    // W1 = W0*A8
    k_matvecTm<<<dim3(5, 2), 512, 0, stream>>>(Eb, WV, 0, 2);    // W{2,3} = W{0,1}*P2
    k_matvecTm<<<dim3(5, 4), 512, 0, stream>>>(Xb, WV, 0, 4);    // W{4..7} = W{0..3}*P4
    k_matvecTm<<<dim3(5, 4), 512, 0, stream>>>(Xb, WV, 4, 8);    // W{8..11} = W{4..7}*P4
    k_matvecTm<<<dim3(5, 1), 512, 0, stream>>>(Xb, WV, 8, 12);   // W12 = W8*P4
    k_terms<<<5, 256, 0, stream>>>(WV, V, TRM);
    k_skernel<<<1, 128, 0, stream>>>(TRM, SVEC);

    // ---- conv chain (bf16 MFMA, tap-fused) ----
    k_conv0<<<dim3(512, 2), 256, 0, stream>>>(x, conv_w0, conv_b0, YBF, ST, ST + 512);
    k_scaleshift<<<1, 512, 0, stream>>>(ST, bn_g, bn_b, SC, SC + 512, 1.0 / (double)BM);
    for (int l = 1; l <= 4; ++l) {
        k_bnrelu<<<13312, 256, 0, stream>>>(YBF, SC + (l - 1) * 1024, SC + (l - 1) * 1024 + 512, ABF);
        k_convm<<<dim3(416, 4), 256, 0, stream>>>(ABF, WT2 + (size_t)(l - 1) * 3 * 262144,
                                                  conv_b + (l - 1) * 512, YBF,
                                                  ST + l * 1024, ST + l * 1024 + 512);
        k_scaleshift<<<1, 512, 0, stream>>>(ST + l * 1024, bn_g + l * 512, bn_b + l * 512,
                                            SC + l * 1024, SC + l * 1024 + 512, 1.0 / (double)BM);
    }
    k_pool<<<dim3(512, 2), 256, 0, stream>>>(YBF, SC + 4 * 1024, SC + 4 * 1024 + 512, SVEC, G);

    // ---- head ----
    k_t512<<<dim3(8, 8, 2), 256, 0, stream>>>(proj_w, PJT, fc1_w, F1T);
    mm(stream, 8, 8, 1, G, 0, 512, PJT, 0, 512, POOL, 0, 512, 512, 5, 1.0f, 0.0f, proj_b, 0, SVEC + 104, 0, 0);
    mm(stream, 8, 8, 1, POOL, 0, 512, F1T, 0, 512, Zb, 0, 512, 512, 6, 1.0f, 0.0f, fc1_b, 0, nullptr, 0, 0);
    k_fcstats<<<16, 256, 0, stream>>>(Zb, ST + 5 * 1024, ST + 5 * 1024 + 512);
    k_final<<<512, 256, 0, stream>>>(Zb, ST + 5 * 1024, fbn_g, fbn_b, fc2_w, fc2_b, outp);
}

// Round 4
// 1872.914 us; speedup vs baseline: 3.5925x; 1.2395x over previous
//
#include <hip/hip_runtime.h>
#include <cstdio>
#include <cmath>
#include <cstdint>

// ---------------- problem constants ----------------
constexpr int BM = 512 * 104;       // 53248 rows
constexpr float BN_EPS = 1e-5f;

// ---------------- workspace layout (bytes) ----------------
constexpr size_t SZ_BF   = (size_t)BM * 512 * 2;           // 54,525,952
constexpr size_t SZ_MAT5 = (size_t)5 * 512 * 512 * 4;      // 5,242,880
constexpr size_t OFF_YB0 = 0;                              // conv ping buffer (bf16 raw y)
constexpr size_t OFF_YB1 = OFF_YB0 + SZ_BF;                // conv pong buffer
constexpr size_t OFF_WT2 = OFF_YB1 + SZ_BF;                // conv weights [4][3][co][ci] bf16
constexpr size_t OFF_X   = OFF_WT2 + 6291456;              // X=0.1A -> A2
constexpr size_t OFF_T1  = OFF_X   + SZ_MAT5;              // P -> A4
constexpr size_t OFF_T2  = OFF_T1  + SZ_MAT5;              // X2 -> A8
constexpr size_t OFF_E   = OFF_T2  + SZ_MAT5;              // E = expm(0.1A) - I
constexpr size_t OFF_MW  = OFF_E   + SZ_MAT5;              // S -> inv(S)
constexpr size_t OFF_P2  = OFF_MW  + SZ_MAT5;              // A16
constexpr size_t OFF_P4  = OFF_P2  + SZ_MAT5;              // A32
constexpr size_t OFF_ROWT= OFF_P4  + SZ_MAT5;              // [5][64][512]
constexpr size_t OFF_COLS= OFF_ROWT + 655360;              // [5][512][64] ping
constexpr size_t OFF_COLS2=OFF_COLS + 655360;              // pong
constexpr size_t OFF_PIVI= OFF_COLS2 + 655360;             // [5][64][64]
constexpr size_t OFF_PJT = OFF_PIVI + 81920;               // proj_w^T
constexpr size_t OFF_F1T = OFF_PJT + 1048576;              // fc1_w^T
constexpr size_t OFF_G   = OFF_F1T + 1048576;              // g[b][h]
constexpr size_t OFF_POOL= OFF_G   + 1048576;              // pooled[b][o]
constexpr size_t OFF_Z   = OFF_POOL + 1048576;             // fc1 out
constexpr size_t OFF_ST  = OFF_Z   + 1048576;              // fp64 stats [6][2][512]
constexpr size_t OFF_U   = OFF_ST  + 49152;                // u[5][512]
constexpr size_t OFF_SV  = OFF_U   + 10240;                // residual r[5][512]
constexpr size_t OFF_V   = OFF_SV  + 10240;                // V[5][8][512]
constexpr size_t OFF_WV  = OFF_V   + 81920;                // W[5][13][512]
constexpr size_t OFF_S   = OFF_WV  + 133120;               // s[104] + sbar
constexpr size_t WS_NEED = OFF_S + 512;

// ---------------- bf16 helpers ----------------
__device__ __forceinline__ float bf2f(unsigned short u) {
    union { uint32_t i; float f; } x; x.i = (uint32_t)u << 16; return x.f;
}
__device__ __forceinline__ unsigned short f2bf(float f) {
    union { float f; uint32_t i; } x; x.f = f;
    uint32_t r = x.i + 0x7FFFu + ((x.i >> 16) & 1u);
    return (unsigned short)(r >> 16);
}

typedef __bf16 bf16x8 __attribute__((ext_vector_type(8)));
typedef float  f32x4  __attribute__((ext_vector_type(4)));

__device__ __forceinline__ void gld16(const void* g, void* l) {
    __builtin_amdgcn_global_load_lds((const __attribute__((address_space(1))) uint32_t*)g,
                                     (__attribute__((address_space(3))) uint32_t*)l, 16, 0, 0);
}

// ================= ZOH: build X = 0.1*A, S = A + 0.001 I, COLS p=0, W0=C =================
__global__ void k_build(const float* __restrict__ Aall, float* __restrict__ X, float* __restrict__ MW,
                        float* __restrict__ COLSa, const float* __restrict__ Call, float* __restrict__ WV)
{
    long i = (long)blockIdx.x * 256 + threadIdx.x;     // 5*262144 total
    float a = Aall[i];
    X[i] = 0.1f * a;
    int z = (int)(i >> 18);
    int rc = (int)(i & 262143);
    int r = rc >> 9, c = rc & 511;
    float mw = a + ((r == c) ? 0.001f : 0.0f);
    MW[i] = mw;
    if (c < 64) COLSa[(long)z * 32768 + r * 64 + c] = mw;
    if (i < 2560) WV[(i >> 9) * 6656 + (i & 511)] = Call[i];
}

// ================= generic batched 64x64-tile fp32 matmul =================
// mode 0: C = acc
// mode 1: C = acc + 2*aux + I                  (A2 = E*E + 2E + I)
// mode 2: C = acc + aux                        (E = X2*P + X)
// mode 3: GJ row-scale: C = acc, cols [pc,pc+64) = aux[row][col-pc]
// mode 5: C = acc + aux[col]*aux2[0]
// mode 7: C = acc (=X2); Cp = 0.5I + aux/6 + acc/24
// mode 8: C = acc + aux[col]; fp64 column stats -> st1/st2
__global__ __launch_bounds__(256) void k_mm(
    const float* __restrict__ A, long sA, int lda,
    const float* __restrict__ Bm, long sB, int ldb,
    float* __restrict__ C, long sC, int ldc,
    int K, int mode,
    const float* __restrict__ aux, long sAux,
    const float* __restrict__ aux2, float* __restrict__ Cp,
    double* __restrict__ st1, double* __restrict__ st2, int pc)
{
    __shared__ float sm[2 * 32 * 68];
    float* As = sm;
    float* Bs = sm + 32 * 68;
    int z = blockIdx.z;
    A  += (long)z * sA;
    Bm += (long)z * sB;
    C  += (long)z * sC;
    if (aux) aux += (long)z * sAux;
    int m0 = blockIdx.x * 64, n0 = blockIdx.y * 64;
    int tid = threadIdx.x;
    int tx = tid & 15, ty = tid >> 4;
    float acc[4][4] = {};
    for (int k0 = 0; k0 < K; k0 += 32) {
        __syncthreads();
#pragma unroll
        for (int it = 0; it < 2; ++it) {
            int s = it * 256 + tid;
            int mm = s >> 3, k4 = (s & 7) * 4;
            float4 v = *(const float4*)&A[(long)(m0 + mm) * lda + k0 + k4];
            As[(k4 + 0) * 68 + mm] = v.x;
            As[(k4 + 1) * 68 + mm] = v.y;
            As[(k4 + 2) * 68 + mm] = v.z;
            As[(k4 + 3) * 68 + mm] = v.w;
        }
#pragma unroll
        for (int it = 0; it < 2; ++it) {
            int s = it * 256 + tid;
            int kk = s >> 4, n4 = (s & 15) * 4;
            *(float4*)&Bs[kk * 68 + n4] = *(const float4*)&Bm[(long)(k0 + kk) * ldb + n0 + n4];
        }
        __syncthreads();
#pragma unroll 8
        for (int kk = 0; kk < 32; ++kk) {
            float4 a = *(const float4*)&As[kk * 68 + ty * 4];
            float4 b = *(const float4*)&Bs[kk * 68 + tx * 4];
            float av[4] = {a.x, a.y, a.z, a.w};
            float bv[4] = {b.x, b.y, b.z, b.w};
#pragma unroll
            for (int i = 0; i < 4; ++i)
#pragma unroll
                for (int j = 0; j < 4; ++j)
                    acc[i][j] = fmaf(av[i], bv[j], acc[i][j]);
        }
    }
    float sc2 = (mode == 5) ? aux2[0] : 0.0f;
    float cs1[4] = {0, 0, 0, 0}, cs2[4] = {0, 0, 0, 0};
#pragma unroll
    for (int i = 0; i < 4; ++i) {
        int row = m0 + ty * 4 + i;
        int col0 = n0 + tx * 4;
        long base = (long)row * ldc + col0;
        float v[4];
#pragma unroll
        for (int j = 0; j < 4; ++j) v[j] = acc[i][j];
        if (mode == 1) {
            for (int j = 0; j < 4; ++j) {
                int col = col0 + j;
                v[j] = v[j] + 2.0f * aux[(long)row * 512 + col] + ((row == col) ? 1.0f : 0.0f);
            }
        } else if (mode == 2) {
            for (int j = 0; j < 4; ++j)
                v[j] = v[j] + aux[(long)row * 512 + col0 + j];
        } else if (mode == 3) {
            bool inP = (col0 >= pc && col0 < pc + 64);
            if (inP)
                for (int j = 0; j < 4; ++j) v[j] = aux[row * 64 + (col0 + j - pc)];
        } else if (mode == 5) {
            for (int j = 0; j < 4; ++j) v[j] += aux[col0 + j] * sc2;
        } else if (mode == 7) {
            float pv[4];
            for (int j = 0; j < 4; ++j) {
                int col = col0 + j;
                pv[j] = ((row == col) ? 0.5f : 0.0f) + aux[(long)row * 512 + col] * (1.0f / 6.0f)
                        + v[j] * (1.0f / 24.0f);
            }
            *(float4*)&Cp[base] = make_float4(pv[0], pv[1], pv[2], pv[3]);
        } else if (mode == 8) {
            for (int j = 0; j < 4; ++j) {
                v[j] += aux[col0 + j];
                cs1[j] += v[j]; cs2[j] += v[j] * v[j];
            }
        }
        *(float4*)&C[base] = make_float4(v[0], v[1], v[2], v[3]);
    }
    if (mode == 8) {
        __syncthreads();
        float* s1s = sm;           // [16][64]
        float* s2s = sm + 1024;
#pragma unroll
        for (int j = 0; j < 4; ++j) {
            s1s[ty * 64 + tx * 4 + j] = cs1[j];
            s2s[ty * 64 + tx * 4 + j] = cs2[j];
        }
        __syncthreads();
        if (tid < 64) {
            double a = 0.0, b = 0.0;
#pragma unroll
            for (int t = 0; t < 16; ++t) { a += s1s[t * 64 + tid]; b += s2s[t * 64 + tid]; }
            atomicAdd(&st1[n0 + tid], a);
            atomicAdd(&st2[n0 + tid], b);
        }
    }
}

// ================= fused GJ elimination step =================
__global__ __launch_bounds__(256) void k_elim(
    const float* __restrict__ COLSc, const float* __restrict__ ROWT,
    float* __restrict__ MW, float* __restrict__ COLSn, int pr, int pcn)
{
    int z = blockIdx.z;
    COLSc += (long)z * 32768; ROWT += (long)z * 32768;
    MW += (long)z * 262144; COLSn += (long)z * 32768;
    int m0 = blockIdx.x * 64, n0 = blockIdx.y * 64;
    int tid = threadIdx.x;
    if (m0 == pr) {
        for (int it = 0; it < 16; ++it) {
            int idx = it * 256 + tid;
            int r = idx >> 6, c = idx & 63;
            float v = ROWT[r * 512 + n0 + c];
            MW[(long)(pr + r) * 512 + n0 + c] = v;
            if (n0 == pcn) COLSn[(pr + r) * 64 + c] = v;
        }
        return;
    }
    __shared__ float As[64 * 68];
    __shared__ float Bs[64 * 68];
    {
        int m = tid >> 2, kb = (tid & 3) * 16;
#pragma unroll
        for (int u = 0; u < 4; ++u) {
            float4 v = *(const float4*)&COLSc[(m0 + m) * 64 + kb + u * 4];
            As[(kb + u * 4 + 0) * 68 + m] = v.x;
            As[(kb + u * 4 + 1) * 68 + m] = v.y;
            As[(kb + u * 4 + 2) * 68 + m] = v.z;
            As[(kb + u * 4 + 3) * 68 + m] = v.w;
        }
        int kr = tid >> 2, nb = (tid & 3) * 16;
#pragma unroll
        for (int u = 0; u < 4; ++u)
            *(float4*)&Bs[kr * 68 + nb + u * 4] = *(const float4*)&ROWT[kr * 512 + n0 + nb + u * 4];
    }
    __syncthreads();
    int tx = tid & 15, ty = tid >> 4;
    float acc[4][4] = {};
#pragma unroll 8
    for (int kk = 0; kk < 64; ++kk) {
        float4 a = *(const float4*)&As[kk * 68 + ty * 4];
        float4 b = *(const float4*)&Bs[kk * 68 + tx * 4];
        float av[4] = {a.x, a.y, a.z, a.w};
        float bv[4] = {b.x, b.y, b.z, b.w};
#pragma unroll
        for (int i = 0; i < 4; ++i)
#pragma unroll
            for (int j = 0; j < 4; ++j)
                acc[i][j] = fmaf(av[i], bv[j], acc[i][j]);
    }
    bool inP = (n0 == pr);
#pragma unroll
    for (int i = 0; i < 4; ++i) {
        int row = m0 + ty * 4 + i;
        int col0 = n0 + tx * 4;
        long base = (long)row * 512 + col0;
        float ov[4] = {0.f, 0.f, 0.f, 0.f};
        if (!inP) {
            float4 oldv = *(const float4*)&MW[base];
            ov[0] = oldv.x; ov[1] = oldv.y; ov[2] = oldv.z; ov[3] = oldv.w;
        }
        float v[4];
#pragma unroll
        for (int j = 0; j < 4; ++j) v[j] = ov[j] - acc[i][j];
        *(float4*)&MW[base] = make_float4(v[0], v[1], v[2], v[3]);
        if (n0 == pcn)
            *(float4*)&COLSn[row * 64 + (col0 - pcn)] = make_float4(v[0], v[1], v[2], v[3]);
    }
}

// ================= pivoted 64x64 Gauss-Jordan inverse in LDS (parallel argmax) =================
__global__ __launch_bounds__(256) void k_inv64(float* __restrict__ MW, int pblk, float* __restrict__ PIVI)
{
    __shared__ float mat[64 * 65];
    __shared__ float fv[64];
    __shared__ int perm[64];
    __shared__ int arr[64];
    __shared__ int pividx;
    __shared__ float dv;
    int z = blockIdx.x;
    float* Mg = MW + (long)z * 262144 + (long)pblk * 64 * 512 + pblk * 64;
    int tid = threadIdx.x;
    for (int it = 0; it < 16; ++it) {
        int idx = it * 256 + tid;
        int r = idx >> 6, c = idx & 63;
        mat[r * 65 + c] = Mg[r * 512 + c];
    }
    __syncthreads();
    for (int j = 0; j < 64; ++j) {
        if (tid < 64) {
            float v = (tid >= j) ? fabsf(mat[tid * 65 + j]) : -1.0f;
            int idx = tid;
#pragma unroll
            for (int off = 32; off; off >>= 1) {
                float ov = __shfl_down(v, off);
                int oi = __shfl_down(idx, off);
                if (ov > v) { v = ov; idx = oi; }
            }
            if (tid == 0) pividx = idx;
        }
        __syncthreads();
        int r = pividx;
        if (tid < 64) {
            if (r != j) {
                float tj = mat[j * 65 + tid], tr = mat[r * 65 + tid];
                mat[j * 65 + tid] = tr; mat[r * 65 + tid] = tj;
            }
            if (tid == 0) perm[j] = r;
        }
        __syncthreads();
        if (tid < 64) {
            float piv = mat[j * 65 + j];
            float d = 1.0f / piv;
            fv[tid] = mat[tid * 65 + j];
            mat[j * 65 + tid] = (tid == j) ? d : mat[j * 65 + tid] * d;
            if (tid == 0) dv = d;
        }
        __syncthreads();
        {
            int i = tid & 63, c0 = (tid >> 6) * 16;
            if (i != j) {
                float f = fv[i];
                float dd = dv;
#pragma unroll
                for (int u = 0; u < 16; ++u) {
                    int c = c0 + u;
                    float val = mat[i * 65 + c] - f * mat[j * 65 + c];
                    if (c == j) val = -f * dd;
                    mat[i * 65 + c] = val;
                }
            }
        }
        __syncthreads();
    }
    if (tid == 0) {
        for (int c = 0; c < 64; ++c) arr[c] = c;
        for (int j = 63; j >= 0; --j) { int r = perm[j]; int t = arr[j]; arr[j] = arr[r]; arr[r] = t; }
    }
    __syncthreads();
    float* Pg = PIVI + z * 4096;
    for (int it = 0; it < 16; ++it) {
        int idx = it * 256 + tid;
        int r = idx >> 6, c = idx & 63;
        Pg[r * 64 + c] = mat[r * 65 + arr[c]];
    }
}

// ================= batched matvec: y = alpha*(A x) + beta*x (B_bar path) =================
__global__ void k_matvecA(const float* __restrict__ A, long sA,
                          const float* __restrict__ x, long sx,
                          float* __restrict__ y, long sy,
                          const float* __restrict__ sub, long ssub,
                          float alpha, float beta, int accum)
{
    int row = blockIdx.x, z = blockIdx.y, lane = threadIdx.x;
    A += (long)z * sA; x += (long)z * sx; y += (long)z * sy;
    if (sub) sub += (long)z * ssub;
    const float* ar = A + (long)row * 512;
    double acc = 0.0;
#pragma unroll
    for (int m = 0; m < 8; ++m) {
        int k = lane + m * 64;
        acc += (double)ar[k] * (double)x[k];
    }
    for (int off = 32; off; off >>= 1) acc += __shfl_down(acc, off);
    if (lane == 0) {
        float val = alpha * (float)acc + beta * x[row];
        if (sub) val = sub[row] - val;
        if (accum) y[row] += val; else y[row] = val;
    }
}

// ================= merged V/W chain multi-task matvec =================
struct VWT { long a[8]; long x[8]; long y[8]; float al[8]; float be[8]; int ty[8]; };
__global__ void k_vw(const char* __restrict__ ws, VWT T)
{
    int g = blockIdx.x, z = blockIdx.y, t = blockIdx.z;
    int lane = threadIdx.x;
    const float* A = (const float*)(ws + T.a[t]) + (long)z * 262144;
    int ty = T.ty[t];
    long vs = ty ? 6656 : 4096;
    const float* x = (const float*)(ws + T.x[t]) + (long)z * vs;
    float* yv = (float*)(ws + T.y[t]) + (long)z * vs;
    if (ty == 0) {
        float xm[8];
#pragma unroll
        for (int m = 0; m < 8; ++m) xm[m] = x[lane + m * 64];
        float alpha = T.al[t], beta = T.be[t];
        for (int r0 = 0; r0 < 64; ++r0) {
            int row = g * 64 + r0;
            const float* ar = A + (long)row * 512;
            double acc = 0.0;
#pragma unroll
            for (int m = 0; m < 8; ++m) acc += (double)ar[lane + m * 64] * (double)xm[m];
            for (int off = 32; off; off >>= 1) acc += __shfl_down(acc, off);
            if (lane == 0) yv[row] = alpha * (float)acc + beta * x[row];
        }
    } else {
        __shared__ float xl[512];
#pragma unroll
        for (int m = 0; m < 8; ++m) xl[lane + m * 64] = x[lane + m * 64];
        __syncthreads();
        int c = g * 64 + lane;
        double acc = 0.0;
#pragma unroll 8
        for (int j = 0; j < 512; ++j) acc += (double)A[(long)j * 512 + c] * (double)xl[j];
        yv[c] = (float)acc;
    }
}

// ================= terms + s-kernel fused =================
__global__ __launch_bounds__(512) void k_termsk(const float* __restrict__ WV, const float* __restrict__ V,
                                                float* __restrict__ svec)
{
    __shared__ float tl[520];
    __shared__ float invn[5];
    __shared__ float red[2];
    int tid = threadIdx.x;
    for (int t = tid; t < 520; t += 512) {
        int z = t / 104, d = t - z * 104;
        int j = d >> 3, i = d & 7;
        const float* wp = WV + z * 6656 + j * 512;
        const float* vp = V + z * 4096 + i * 512;
        float acc = 0.0f;
#pragma unroll 8
        for (int k = 0; k < 512; ++k) acc += wp[k] * vp[k];
        tl[t] = acc;
    }
    __syncthreads();
    int w = tid >> 6, lane = tid & 63;
    if (w < 5) {
        float a = tl[w * 104 + lane]; a = a * a;
        if (lane < 40) { float b = tl[w * 104 + 64 + lane]; a += b * b; }
#pragma unroll
        for (int off = 32; off; off >>= 1) a += __shfl_down(a, off);
        if (lane == 0) invn[w] = 1.0f / (sqrtf(a) + 1e-6f);
    }
    __syncthreads();
    float s = 0.0f;
    if (tid < 104) {
        s = 1.0f;
        for (int l = 0; l < 5; ++l) s *= tl[l * 104 + (103 - tid)] * invn[l];
        svec[tid] = s;
    }
    if (tid < 128) {
        float v = (tid < 104) ? s : 0.0f;
#pragma unroll
        for (int off = 32; off; off >>= 1) v += __shfl_down(v, off);
        if ((tid & 63) == 0) red[tid >> 6] = v;
    }
    __syncthreads();
    if (tid == 0) svec[104] = (red[0] + red[1]) * (1.0f / 104.0f);
}

// ================= conv0 (1->H) + stats, bf16 out =================
__global__ void k_conv0(const float* __restrict__ x, const float* __restrict__ w0, const float* __restrict__ b0,
                        unsigned short* __restrict__ y, double* __restrict__ s1g, double* __restrict__ s2g)
{
    int b = blockIdx.x;
    int c = blockIdx.y * 256 + threadIdx.x;
    float w_0 = w0[c * 3 + 0], w_1 = w0[c * 3 + 1], w_2 = w0[c * 3 + 2], bb = b0[c];
    const float* xb = x + b * 104;
    unsigned short* yb = y + (long)b * 104 * 512 + c;
    float xm2 = 0.0f, xm1 = 0.0f;
    float s1 = 0.0f, s2 = 0.0f;
    for (int t = 0; t < 104; ++t) {
        float x0 = xb[t];
        float v = w_0 * xm2 + w_1 * xm1 + w_2 * x0 + bb;
        yb[t * 512] = f2bf(v);
        s1 += v; s2 += v * v;
        xm2 = xm1; xm1 = x0;
    }
    atomicAdd(&s1g[c], (double)s1);
    atomicAdd(&s2g[c], (double)s2);
}

// conv weights -> bf16 [l][tap][co][ci]
__global__ void k_wt2(const float* __restrict__ W, unsigned short* __restrict__ Wt2)
{
    int co = blockIdx.x, l = blockIdx.y, tid = threadIdx.x;
    const float* src = W + (long)(l * 512 + co) * 512 * 3;
    unsigned short* dst = Wt2 + (long)l * 3 * 262144 + ((long)co << 9);
#pragma unroll
    for (int q = 0; q < 2; ++q) {
        int ci = tid * 2 + q;
        float f0 = src[ci * 3 + 0], f1 = src[ci * 3 + 1], f2 = src[ci * 3 + 2];
        dst[ci] = f2bf(f0);
        dst[262144 + ci] = f2bf(f1);
        dst[524288 + ci] = f2bf(f2);
    }
}

// ================= MFMA conv GEMM, tap-fused, BN+ReLU fused on A staging =================
__global__ __launch_bounds__(256) void k_convm(
    const unsigned short* __restrict__ act,      // raw y of previous layer
    const unsigned short* __restrict__ Wt2,      // layer base [3][512][512]
    const float* __restrict__ bias,
    const double* __restrict__ STin,             // prev layer stats [2][512]
    const float* __restrict__ gam, const float* __restrict__ bet,
    unsigned short* __restrict__ yout,
    double* __restrict__ s1g, double* __restrict__ s2g)
{
    __shared__ __align__(16) unsigned short As[130 * 32];     // 8320 B
    __shared__ __align__(16) unsigned short Bs[3 * 128 * 32]; // 24576 B
    __shared__ float SCs[512];
    __shared__ float SHs[512];
    int tid = threadIdx.x;
    int m0 = blockIdx.x * 128, co0 = blockIdx.y * 128;
    int w = tid >> 6, lane = tid & 63;
    int wr = (w >> 1) * 64, wc = (w & 1) * 64;
    int fr = lane & 15, fkb = (lane >> 4) * 8, quad = lane >> 4;

    // BN scale/shift tables (fp64 stats -> f32)
    const double invN = 1.0 / (double)BM;
    for (int c = tid; c < 512; c += 256) {
        double mn = STin[c] * invN;
        double var = STin[512 + c] * invN - mn * mn;
        double rs = 1.0 / sqrt(var + (double)BN_EPS);
        double scd = (double)gam[c] * rs;
        SCs[c] = (float)scd;
        SHs[c] = (float)((double)bet[c] - mn * scd);
    }

    bool valid[4][3];
#pragma unroll
    for (int i = 0; i < 4; ++i) {
        int R = m0 + wr + i * 16 + fr;
        int t = R % 104;
#pragma unroll
        for (int tau = 0; tau < 3; ++tau) valid[i][tau] = (t + tau >= 2);
    }
    int ka = (tid & 3) * 8;
    int g0 = m0 - 2 + (tid >> 2); if (g0 < 0) g0 = 0;
    int g1 = m0 + 62 + (tid >> 2);
    int g2 = m0 + 126 + (tid >> 2);
    const unsigned short* pa0 = act + (long)g0 * 512 + ka;
    const unsigned short* pa1 = act + (long)g1 * 512 + ka;
    const unsigned short* pa2 = act + (long)g2 * 512 + ka;
    const unsigned short* pb[6];
#pragma unroll
    for (int it = 0; it < 6; ++it) {
        int c = it * 256 + tid;
        int tau = c >> 9, r = (c >> 2) & 127, kq = (c & 3) * 8;
        pb[it] = Wt2 + ((long)tau << 18) + ((long)(co0 + r) << 9) + kq;
    }

    f32x4 zero4 = {0.f, 0.f, 0.f, 0.f};
    f32x4 acc[4][4];
#pragma unroll
    for (int i = 0; i < 4; ++i)
#pragma unroll
        for (int j = 0; j < 4; ++j) acc[i][j] = zero4;
    bf16x8 zer = {0, 0, 0, 0, 0, 0, 0, 0};

#pragma unroll 1
    for (int s = 0; s < 16; ++s) {
        int ci0 = s * 32;
        int cb = ci0 + ka;
        __syncthreads();
        // B: async global->LDS
#pragma unroll
        for (int it = 0; it < 6; ++it)
            gld16(pb[it] + ci0, &Bs[it * 2048 + tid * 8]);
        // A: VGPR load + BN+ReLU + ds_write
        float4 s0 = *(const float4*)&SCs[cb], s1v = *(const float4*)&SCs[cb + 4];
        float4 h0 = *(const float4*)&SHs[cb], h1v = *(const float4*)&SHs[cb + 4];
        float ss[8] = {s0.x, s0.y, s0.z, s0.w, s1v.x, s1v.y, s1v.z, s1v.w};
        float hh[8] = {h0.x, h0.y, h0.z, h0.w, h1v.x, h1v.y, h1v.z, h1v.w};
        int nrep = (tid < 8) ? 3 : 2;
        const unsigned short* pas[3] = {pa0, pa1, pa2};
#pragma unroll
        for (int rep = 0; rep < 3; ++rep) {
            if (rep < nrep) {
                uint4 v = *(const uint4*)(pas[rep] + ci0);
                unsigned short u[8];
                u[0] = (unsigned short)(v.x & 0xFFFF); u[1] = (unsigned short)(v.x >> 16);
                u[2] = (unsigned short)(v.y & 0xFFFF); u[3] = (unsigned short)(v.y >> 16);
                u[4] = (unsigned short)(v.z & 0xFFFF); u[5] = (unsigned short)(v.z >> 16);
                u[6] = (unsigned short)(v.w & 0xFFFF); u[7] = (unsigned short)(v.w >> 16);
                unsigned short o[8];
#pragma unroll
                for (int q = 0; q < 8; ++q)
                    o[q] = f2bf(fmaxf(fmaf(bf2f(u[q]), ss[q], hh[q]), 0.0f));
                uint4 pk;
                pk.x = (uint32_t)o[0] | ((uint32_t)o[1] << 16);
                pk.y = (uint32_t)o[2] | ((uint32_t)o[3] << 16);
                pk.z = (uint32_t)o[4] | ((uint32_t)o[5] << 16);
                pk.w = (uint32_t)o[6] | ((uint32_t)o[7] << 16);
                *(uint4*)&As[rep * 2048 + tid * 8] = pk;
            }
        }
        __syncthreads();
#pragma unroll
        for (int tau = 0; tau < 3; ++tau) {
            bf16x8 af[4], bfr[4];
#pragma unroll
            for (int i = 0; i < 4; ++i) {
                bf16x8 raw = *(const bf16x8*)&As[(wr + i * 16 + fr + tau) * 32 + fkb];
                af[i] = valid[i][tau] ? raw : zer;
            }
#pragma unroll
            for (int j = 0; j < 4; ++j)
                bfr[j] = *(const bf16x8*)&Bs[tau * 4096 + (wc + j * 16 + fr) * 32 + fkb];
#pragma unroll
            for (int i = 0; i < 4; ++i)
#pragma unroll
                for (int j = 0; j < 4; ++j)
                    acc[i][j] = __builtin_amdgcn_mfma_f32_16x16x32_bf16(af[i], bfr[j], acc[i][j], 0, 0, 0);
        }
    }
    // epilogue: bias, bf16 store, per-channel stats
    float bcol[4], s1[4] = {0, 0, 0, 0}, s2[4] = {0, 0, 0, 0};
#pragma unroll
    for (int jt = 0; jt < 4; ++jt) bcol[jt] = bias[co0 + wc + jt * 16 + fr];
#pragma unroll
    for (int i = 0; i < 4; ++i) {
        int rbase = m0 + wr + i * 16 + quad * 4;
#pragma unroll
        for (int jt = 0; jt < 4; ++jt) {
            int col = co0 + wc + jt * 16 + fr;
#pragma unroll
            for (int r = 0; r < 4; ++r) {
                float v = acc[i][jt][r] + bcol[jt];
                yout[(long)(rbase + r) * 512 + col] = f2bf(v);
                s1[jt] += v; s2[jt] += v * v;
            }
        }
    }
#pragma unroll
    for (int jt = 0; jt < 4; ++jt) {
        s1[jt] += __shfl_xor(s1[jt], 16); s1[jt] += __shfl_xor(s1[jt], 32);
        s2[jt] += __shfl_xor(s2[jt], 16); s2[jt] += __shfl_xor(s2[jt], 32);
    }
    __syncthreads();
    float* st = (float*)As;   // [8][64]
    if (lane < 16) {
#pragma unroll
        for (int jt = 0; jt < 4; ++jt) {
            st[w * 64 + jt * 16 + lane] = s1[jt];
            st[256 + w * 64 + jt * 16 + lane] = s2[jt];
        }
    }
    __syncthreads();
    if (tid < 128) {
        int half = tid >> 6, cl = tid & 63;
        float a = st[half * 64 + cl] + st[(half + 2) * 64 + cl];
        float b = st[256 + half * 64 + cl] + st[256 + (half + 2) * 64 + cl];
        atomicAdd(&s1g[co0 + tid], (double)a);
        atomicAdd(&s2g[co0 + tid], (double)b);
    }
}

// ================= pool: g[b][h] = (1/M) sum_t s[t]*(relu(bn4(y4)) + pe[t][h]) =================
__global__ void k_pool(const unsigned short* __restrict__ y4, const double* __restrict__ ST4,
                       const float* __restrict__ gam, const float* __restrict__ bet,
                       const float* __restrict__ svec, float* __restrict__ g)
{
    __shared__ float sl[104];
    int b = blockIdx.x;
    int c = blockIdx.y * 256 + threadIdx.x;
    if (threadIdx.x < 104) sl[threadIdx.x] = svec[threadIdx.x];
    __syncthreads();
    const double invN = 1.0 / (double)BM;
    double mn = ST4[c] * invN;
    double var = ST4[512 + c] * invN - mn * mn;
    double rs = 1.0 / sqrt(var + (double)BN_EPS);
    double scd = (double)gam[c] * rs;
    float sc = (float)scd, sh = (float)((double)bet[c] - mn * scd);
    int he = c & ~1;
    float div = expf((float)he * (-0.017988946039015984f));   // -ln(10000)/512
    float acc = 0.0f;
    const unsigned short* yb = y4 + (long)b * 104 * 512 + c;
    for (int t = 0; t < 104; ++t) {
        float v = bf2f(yb[t * 512]);
        float hn = fmaxf(fmaf(v, sc, sh), 0.0f);
        float arg = (float)t * div;
        float pe = (c & 1) ? cosf(arg) : sinf(arg);
        acc += sl[t] * (hn + pe);
    }
    g[(long)b * 512 + c] = acc * (1.0f / 104.0f);
}

// ================= dual 512x512 transpose =================
__global__ void k_t512(const float* __restrict__ in0, float* __restrict__ out0,
                       const float* __restrict__ in1, float* __restrict__ out1)
{
    __shared__ float tile[64 * 68];
    const float* in = blockIdx.z ? in1 : in0;
    float* outp = blockIdx.z ? out1 : out0;
    int bx = blockIdx.x, by = blockIdx.y;
    int tid = threadIdx.x;
    for (int it = 0; it < 4; ++it) {
        int s = it * 256 + tid;
        int r = s >> 4, c4 = (s & 15) * 4;
        *(float4*)&tile[r * 68 + c4] = *(const float4*)&in[(long)(bx * 64 + r) * 512 + by * 64 + c4];
    }
    __syncthreads();
    for (int it = 0; it < 4; ++it) {
        int s = it * 256 + tid;
        int r = s >> 4, c4 = (s & 15) * 4;
        float4 v;
        v.x = tile[(c4 + 0) * 68 + r];
        v.y = tile[(c4 + 1) * 68 + r];
        v.z = tile[(c4 + 2) * 68 + r];
        v.w = tile[(c4 + 3) * 68 + r];
        *(float4*)&outp[(long)(by * 64 + r) * 512 + bx * 64 + c4] = v;
    }
}

// BN(batch) -> exact GELU -> fc2
__global__ __launch_bounds__(256) void k_final(const float* __restrict__ zin, const double* __restrict__ st,
                                               const float* __restrict__ gam, const float* __restrict__ bet,
                                               const float* __restrict__ w2, const float* __restrict__ b2,
                                               float* __restrict__ outp)
{
    __shared__ float red[256];
    int b = blockIdx.x, tid = threadIdx.x;
    int oo[2] = { tid, tid + 256 };
    float gv[2];
#pragma unroll
    for (int q = 0; q < 2; ++q) {
        int o = oo[q];
        double m = st[o] * (1.0 / 512.0);
        double var = st[512 + o] * (1.0 / 512.0) - m * m;
        double rs = 1.0 / sqrt(var + (double)BN_EPS);
        float xn = (float)(((double)zin[(long)b * 512 + o] - m) * rs * (double)gam[o] + (double)bet[o]);
        gv[q] = 0.5f * xn * (1.0f + erff(xn * 0.70710678118654752f));
    }
    for (int n = 0; n < 5; ++n) {
        float p = gv[0] * w2[n * 512 + oo[0]] + gv[1] * w2[n * 512 + oo[1]];
        red[tid] = p;
        __syncthreads();
        for (int off = 128; off; off >>= 1) { if (tid < off) red[tid] += red[tid + off]; __syncthreads(); }
        if (tid == 0) outp[b * 5 + n] = red[0] + b2[n];
        __syncthreads();
    }
}

// ===================== host side =====================
static void mm(hipStream_t s, int Mt, int Nt, int z,
               const float* A, long sA, int lda,
               const float* B, long sB, int ldb,
               float* C, long sC, int ldc,
               int K, int mode,
               const float* aux = nullptr, long sAux = 0, const float* aux2 = nullptr,
               float* Cp = nullptr, double* st1 = nullptr, double* st2 = nullptr, int pc = 0)
{
    dim3 g(Mt, Nt, z);
    k_mm<<<g, 256, 0, s>>>(A, sA, lda, B, sB, ldb, C, sC, ldc, K, mode, aux, sAux, aux2, Cp, st1, st2, pc);
}

extern "C" void kernel_launch(void* const* d_in, const int* in_sizes, int n_in,
                              void* d_out, int out_size, void* d_ws, size_t ws_size,
                              hipStream_t stream)
{
    (void)in_sizes; (void)n_in; (void)out_size;
    const float* x       = (const float*)d_in[0];
    const float* conv_w0 = (const float*)d_in[1];
    const float* conv_b0 = (const float*)d_in[2];
    const float* conv_w  = (const float*)d_in[3];
    const float* conv_b  = (const float*)d_in[4];
    const float* bn_g    = (const float*)d_in[5];
    const float* bn_b    = (const float*)d_in[6];
    const float* proj_w  = (const float*)d_in[7];
    const float* proj_b  = (const float*)d_in[8];
    const float* A_all   = (const float*)d_in[9];
    const float* B_all   = (const float*)d_in[10];
    const float* C_all   = (const float*)d_in[11];
    const float* fc1_w   = (const float*)d_in[12];
    const float* fc1_b   = (const float*)d_in[13];
    const float* fbn_g   = (const float*)d_in[14];
    const float* fbn_b   = (const float*)d_in[15];
    const float* fc2_w   = (const float*)d_in[16];
    const float* fc2_b   = (const float*)d_in[17];
    float* outp = (float*)d_out;
    char* ws = (char*)d_ws;
    if (ws_size < WS_NEED) { printf("ws too small: %zu < %zu\n", ws_size, WS_NEED); return; }

    unsigned short* YB0 = (unsigned short*)(ws + OFF_YB0);
    unsigned short* YB1 = (unsigned short*)(ws + OFF_YB1);
    unsigned short* WT2 = (unsigned short*)(ws + OFF_WT2);
    float* Xb   = (float*)(ws + OFF_X);
    float* T1   = (float*)(ws + OFF_T1);
    float* T2   = (float*)(ws + OFF_T2);
    float* Eb   = (float*)(ws + OFF_E);
    float* MW   = (float*)(ws + OFF_MW);
    float* P2   = (float*)(ws + OFF_P2);
    float* P4   = (float*)(ws + OFF_P4);
    float* ROWT = (float*)(ws + OFF_ROWT);
    float* COLS1= (float*)(ws + OFF_COLS);
    float* COLS2= (float*)(ws + OFF_COLS2);
    float* PIVI = (float*)(ws + OFF_PIVI);
    float* PJT  = (float*)(ws + OFF_PJT);
    float* F1T  = (float*)(ws + OFF_F1T);
    float* G    = (float*)(ws + OFF_G);
    float* POOL = (float*)(ws + OFF_POOL);
    float* Zb   = (float*)(ws + OFF_Z);
    double* ST  = (double*)(ws + OFF_ST);
    float* U    = (float*)(ws + OFF_U);
    float* SV   = (float*)(ws + OFF_SV);
    float* V    = (float*)(ws + OFF_V);
    float* WV   = (float*)(ws + OFF_WV);
    float* SVEC = (float*)(ws + OFF_S);

    const long SM = 262144;
    hipMemsetAsync(ws + OFF_ST, 0, 49152, stream);

    // ---- conv weights -> bf16 ----
    k_wt2<<<dim3(512, 4), 256, 0, stream>>>(conv_w, WT2);
    // ---- build ----
    k_build<<<5120, 256, 0, stream>>>(A_all, Xb, MW, COLS1, C_all, WV);
    // ---- blocked Gauss-Jordan inverse of S ----
    for (int p = 0; p < 8; ++p) {
        int pc = p * 64;
        float* Cc = (p & 1) ? COLS2 : COLS1;
        float* Cn = (p & 1) ? COLS1 : COLS2;
        k_inv64<<<5, 256, 0, stream>>>(MW, p, PIVI);
        mm(stream, 1, 8, 5, PIVI, 4096, 64, MW + pc * 512, SM, 512, ROWT, 32768, 512, 64, 3,
           PIVI, 4096, nullptr, nullptr, nullptr, nullptr, pc);
        k_elim<<<dim3(8, 8, 5), 256, 0, stream>>>(Cc, ROWT, MW, Cn, pc, pc + 64);
    }
    // ---- expm chain: X2(+P), E, A2, A4, A8, A16, A32 ----
    mm(stream, 8, 8, 5, Xb, SM, 512, Xb, SM, 512, T2, SM, 512, 512, 7, Xb, SM, nullptr, T1);
    mm(stream, 8, 8, 5, T2, SM, 512, T1, SM, 512, Eb, SM, 512, 512, 2, Xb, SM);
    mm(stream, 8, 8, 5, Eb, SM, 512, Eb, SM, 512, Xb, SM, 512, 512, 1, Eb, SM);
    mm(stream, 8, 8, 5, Xb, SM, 512, Xb, SM, 512, T1, SM, 512, 512, 0);
    mm(stream, 8, 8, 5, T1, SM, 512, T1, SM, 512, T2, SM, 512, 512, 0);
    mm(stream, 8, 8, 5, T2, SM, 512, T2, SM, 512, P2, SM, 512, 512, 0);
    mm(stream, 8, 8, 5, P2, SM, 512, P2, SM, 512, P4, SM, 512, 512, 0);
    // ---- B_bar with one fp64-residual refinement step ----
    k_matvecA<<<dim3(512, 5), 64, 0, stream>>>(Eb, SM, B_all, 512, U, 512, nullptr, 0, 0.1f, 0.0f, 0);
    k_matvecA<<<dim3(512, 5), 64, 0, stream>>>(MW, SM, U, 512, V, 4096, nullptr, 0, 1.0f, 0.0f, 0);
    k_matvecA<<<dim3(512, 5), 64, 0, stream>>>(A_all, SM, V, 4096, SV, 512, U, 512, 1.0f, 0.001f, 0);
    k_matvecA<<<dim3(512, 5), 64, 0, stream>>>(MW, SM, SV, 512, V, 4096, nullptr, 0, 1.0f, 0.0f, 1);
    // ---- merged V/W chains ----
    auto Voff = [](int i) { return (long)(OFF_V + (size_t)i * 2048); };
    auto Woff = [](int j) { return (long)(OFF_WV + (size_t)j * 2048); };
    {
        VWT T = {};
        T.a[0] = OFF_E;  T.x[0] = Voff(0); T.y[0] = Voff(1); T.al[0] = 1; T.be[0] = 1; T.ty[0] = 0;
        T.a[1] = OFF_T2; T.x[1] = Woff(0); T.y[1] = Woff(1); T.ty[1] = 1;
        k_vw<<<dim3(8, 5, 2), 64, 0, stream>>>(ws, T);
    }
    {
        VWT T = {};
        T.a[0] = OFF_X;  T.x[0] = Voff(0); T.y[0] = Voff(2); T.al[0] = 1; T.ty[0] = 0;
        T.a[1] = OFF_X;  T.x[1] = Voff(1); T.y[1] = Voff(3); T.al[1] = 1; T.ty[1] = 0;
        T.a[2] = OFF_P2; T.x[2] = Woff(0); T.y[2] = Woff(2); T.ty[2] = 1;
        T.a[3] = OFF_P2; T.x[3] = Woff(1); T.y[3] = Woff(3); T.ty[3] = 1;
        k_vw<<<dim3(8, 5, 4), 64, 0, stream>>>(ws, T);
    }
    {
        VWT T = {};
        for (int i = 0; i < 4; ++i) {
            T.a[i] = OFF_T1; T.x[i] = Voff(i); T.y[i] = Voff(4 + i); T.al[i] = 1; T.ty[i] = 0;
            T.a[4 + i] = OFF_P4; T.x[4 + i] = Woff(i); T.y[4 + i] = Woff(4 + i); T.ty[4 + i] = 1;
        }
        k_vw<<<dim3(8, 5, 8), 64, 0, stream>>>(ws, T);
    }
    {
        VWT T = {};
        for (int i = 0; i < 4; ++i) {
            T.a[i] = OFF_P4; T.x[i] = Woff(4 + i); T.y[i] = Woff(8 + i); T.ty[i] = 1;
        }
        k_vw<<<dim3(8, 5, 4), 64, 0, stream>>>(ws, T);
    }
    {
        VWT T = {};
        T.a[0] = OFF_P4; T.x[0] = Woff(8); T.y[0] = Woff(12); T.ty[0] = 1;
        k_vw<<<dim3(8, 5, 1), 64, 0, stream>>>(ws, T);
    }
    k_termsk<<<1, 512, 0, stream>>>(WV, V, SVEC);

    // ---- conv chain (bf16 MFMA, tap-fused, BN+ReLU fused in staging) ----
    k_conv0<<<dim3(512, 2), 256, 0, stream>>>(x, conv_w0, conv_b0, YB0, ST, ST + 512);
    for (int l = 1; l <= 4; ++l) {
        unsigned short* inb  = (l & 1) ? YB0 : YB1;
        unsigned short* outb = (l & 1) ? YB1 : YB0;
        k_convm<<<dim3(416, 4), 256, 0, stream>>>(inb, WT2 + (size_t)(l - 1) * 3 * 262144,
                                                  conv_b + (l - 1) * 512,
                                                  ST + (l - 1) * 1024, bn_g + (l - 1) * 512, bn_b + (l - 1) * 512,
                                                  outb, ST + l * 1024, ST + l * 1024 + 512);
    }
    k_pool<<<dim3(512, 2), 256, 0, stream>>>(YB0, ST + 4 * 1024, bn_g + 4 * 512, bn_b + 4 * 512, SVEC, G);

    // ---- head ----
    k_t512<<<dim3(8, 8, 2), 256, 0, stream>>>(proj_w, PJT, fc1_w, F1T);
    mm(stream, 8, 8, 1, G, 0, 512, PJT, 0, 512, POOL, 0, 512, 512, 5, proj_b, 0, SVEC + 104);
    mm(stream, 8, 8, 1, POOL, 0, 512, F1T, 0, 512, Zb, 0, 512, 512, 8, fc1_b, 0, nullptr, nullptr,
       ST + 5 * 1024, ST + 5 * 1024 + 512);
    k_final<<<512, 256, 0, stream>>>(Zb, ST + 5 * 1024, fbn_g, fbn_b, fc2_w, fc2_b, outp);
}